// Round 4
// baseline (735.863 us; speedup 1.0000x reference)
//
#include <hip/hip_runtime.h>
#include <hip/hip_bf16.h>
#include <cstddef>

#define NN 100000
#define EE 1600000
#define CC 1000
#define NB ((NN + 255) / 256)   // 391 scan blocks

using short8 = __attribute__((ext_vector_type(8))) short;
using f32x4  = __attribute__((ext_vector_type(4))) float;

__device__ __forceinline__ float bf2f(unsigned int u) {
    union { unsigned int i; float f; } x; x.i = u << 16; return x.f;
}
__device__ __forceinline__ unsigned short f2bf(float f) {
    __hip_bfloat16 h = __float2bfloat16(f);
    return *reinterpret_cast<unsigned short*>(&h);
}

// ---------------- init: rowcnt=0, sums=0, cnt=0 ----------------
__global__ void k_init(int* __restrict__ rowcnt, float* __restrict__ s1,
                       float* __restrict__ s2, float* __restrict__ cnt) {
    int i = blockIdx.x * 256 + threadIdx.x;   // grid covers 128000
    if (i < NN) rowcnt[i] = 0;
    if (i < CC * 128) { s1[i] = 0.f; s2[i] = 0.f; }
    if (i < CC) cnt[i] = 0.f;
}

// ---------------- degree histogram over dst ----------------
__global__ void k_counti(const int* __restrict__ dst, int* __restrict__ rowcnt) {
    int i = blockIdx.x * 256 + threadIdx.x;
    if (i < EE) atomicAdd(&rowcnt[dst[i]], 1);
}

// ---------------- dis = rsqrt(deg+1) ----------------
__global__ void k_dis(const int* __restrict__ rowcnt, float* __restrict__ dis) {
    int i = blockIdx.x * 256 + threadIdx.x;
    if (i < NN) dis[i] = rsqrtf((float)rowcnt[i] + 1.0f);
}

// ---------------- scan step 1: per-block sums ----------------
__global__ void k_blocksum(const int* __restrict__ rowcnt, int* __restrict__ bsum) {
    __shared__ int sd[256];
    int t = threadIdx.x, i = blockIdx.x * 256 + t;
    sd[t] = (i < NN) ? rowcnt[i] : 0;
    __syncthreads();
    for (int s = 128; s > 0; s >>= 1) {
        if (t < s) sd[t] += sd[t + s];
        __syncthreads();
    }
    if (t == 0) bsum[blockIdx.x] = sd[0];
}

// ---------------- scan step 2: exclusive scan of block sums (1 block) ----------------
__global__ void k_scanb(int* __restrict__ bsum) {
    __shared__ int sd[512];
    int t = threadIdx.x;
    int v = (t < NB) ? bsum[t] : 0;
    sd[t] = v;
    __syncthreads();
    for (int off = 1; off < 512; off <<= 1) {
        int x = (t >= off) ? sd[t - off] : 0;
        __syncthreads();
        sd[t] += x;
        __syncthreads();
    }
    if (t < NB) bsum[t] = sd[t] - v;   // exclusive
}

// ---------------- scan step 3: write row offsets, zero rowcnt for reuse ----------------
__global__ void k_writeofs(int* __restrict__ rowcnt, const int* __restrict__ bsum,
                           int* __restrict__ rowofs) {
    __shared__ int sd[256];
    int t = threadIdx.x, i = blockIdx.x * 256 + t;
    int v = (i < NN) ? rowcnt[i] : 0;
    sd[t] = v;
    __syncthreads();
    for (int off = 1; off < 256; off <<= 1) {
        int x = (t >= off) ? sd[t - off] : 0;
        __syncthreads();
        sd[t] += x;
        __syncthreads();
    }
    if (i < NN) {
        rowofs[i] = bsum[blockIdx.x] + sd[t] - v;
        rowcnt[i] = 0;                 // reset for fill pass
    }
    if (i == 0) rowofs[NN] = EE;
}

// ---------------- CSR fill: csr_src + csr_norm sorted by dst ----------------
__global__ void k_fill(const int* __restrict__ src, const int* __restrict__ dst,
                       const float* __restrict__ dis,
                       const int* __restrict__ rowofs, int* __restrict__ rowcnt,
                       int* __restrict__ csr_src, float* __restrict__ csr_norm) {
    int e = blockIdx.x * 256 + threadIdx.x;
    if (e >= EE) return;
    int d = dst[e], s = src[e];
    int pos = rowofs[d] + atomicAdd(&rowcnt[d], 1);
    csr_src[pos] = s;
    csr_norm[pos] = dis[s] * dis[d];
}

// ---------------- weight convert+transpose (all 3): W[K][N] f32 -> Wt[N][K+8] bf16 ----------------
__global__ void k_wconv(const float* __restrict__ W3, unsigned short* __restrict__ W3t,
                        const float* __restrict__ Wc1, unsigned short* __restrict__ Wc1t,
                        const float* __restrict__ Wc2, unsigned short* __restrict__ Wc2t) {
    int y = blockIdx.y;
    int k = blockIdx.x * 256 + threadIdx.x;
    if (y < 320) {              // W3: K=320, N=320
        if (k < 328) W3t[(size_t)y * 328 + k] = (k < 320) ? f2bf(W3[(size_t)k * 320 + y]) : 0;
    } else if (y < 448) {       // Wc1: K=320, N=128
        int n = y - 320;
        if (k < 328) Wc1t[(size_t)n * 328 + k] = (k < 320) ? f2bf(Wc1[(size_t)k * 128 + n]) : 0;
    } else {                    // Wc2: K=128, N=128
        int n = y - 448;
        if (k < 136) Wc2t[(size_t)n * 136 + k] = (k < 128) ? f2bf(Wc2[(size_t)k * 128 + n]) : 0;
    }
}

// ---------------- fused embed + emb3 GEMM: h1 = relu(h0 @ W3 + b3) ----------------
// h0 = [relu(x[:, :7]W1+b1) | relu(x[:,7:]W2+b2) | id] computed into LDS.
// 128-row block, 4 waves (2x2 over 128x64 col-tile), loop 5 col-tiles.
__global__ __launch_bounds__(256) void k_emb3(
    const float* __restrict__ x, const float* __restrict__ id_emb,
    const float* __restrict__ W1, const float* __restrict__ b1,
    const float* __restrict__ W2, const float* __restrict__ b2,
    const unsigned short* __restrict__ W3t, const float* __restrict__ b3,
    unsigned short* __restrict__ h1, int M) {
    __shared__ __align__(16) short h0t[128][328];      // 84 KB, full-K A tile
    __shared__ __align__(16) short BsBuf[64 * 328];    // 42 KB, aliased in phase A
    int t = threadIdx.x;
    int rowBase = blockIdx.x * 128;

    // ---- phase A: build h0 tile in LDS ----
    {
        float* fbuf = (float*)BsBuf;
        float* W1s = fbuf;                 // 7*128
        float* W2s = fbuf + 7 * 128;       // 12*128
        float* b1s = fbuf + 19 * 128;      // 128
        float* b2s = b1s + 128;            // 128
        float* xs  = b2s + 128;            // [128][20]
        for (int i = t; i < 7 * 128; i += 256) W1s[i] = W1[i];
        for (int i = t; i < 12 * 128; i += 256) W2s[i] = W2[i];
        if (t < 128) { b1s[t] = b1[t]; b2s[t] = b2[t]; }
        for (int i = t; i < 128 * 19; i += 256) {
            int r = i / 19, c = i % 19;
            int gr = rowBase + r;
            xs[r * 20 + c] = (gr < M) ? x[(size_t)gr * 19 + c] : 0.f;
        }
        __syncthreads();
        int wid = t >> 6, lane = t & 63;
        for (int n = wid; n < 128; n += 4) {
            int gn = rowBase + n;
            float acc0 = b1s[lane], acc1 = b1s[lane + 64];
            #pragma unroll
            for (int k = 0; k < 7; ++k) {
                float xv = xs[n * 20 + k];
                acc0 += xv * W1s[k * 128 + lane];
                acc1 += xv * W1s[k * 128 + 64 + lane];
            }
            float acc2 = b2s[lane], acc3 = b2s[lane + 64];
            #pragma unroll
            for (int k = 0; k < 12; ++k) {
                float xv = xs[n * 20 + 7 + k];
                acc2 += xv * W2s[k * 128 + lane];
                acc3 += xv * W2s[k * 128 + 64 + lane];
            }
            float idv = (gn < M) ? id_emb[(size_t)gn * 64 + lane] : 0.f;
            h0t[n][lane]        = f2bf(fmaxf(acc0, 0.f));
            h0t[n][64 + lane]   = f2bf(fmaxf(acc1, 0.f));
            h0t[n][128 + lane]  = f2bf(fmaxf(acc2, 0.f));
            h0t[n][192 + lane]  = f2bf(fmaxf(acc3, 0.f));
            h0t[n][256 + lane]  = f2bf(idv);
        }
        __syncthreads();
    }

    // ---- phase B: GEMM over 5 col-tiles of 64 ----
    int wid = t >> 6, lane = t & 63;
    int wm = wid >> 1, wn = wid & 1;
    int fr = lane & 15, g = lane >> 4;
    for (int ct = 0; ct < 5; ++ct) {
        for (int i = t; i < 64 * 41; i += 256) {
            int r = i / 41, c = i % 41;
            *(short8*)&BsBuf[r * 328 + c * 8] =
                *(const short8*)(W3t + (size_t)(ct * 64 + r) * 328 + c * 8);
        }
        __syncthreads();
        f32x4 acc[4][2] = {};
        #pragma unroll
        for (int kb = 0; kb < 320; kb += 32) {
            short8 bA = *(const short8*)&BsBuf[(wn * 32 + fr) * 328 + kb + g * 8];
            short8 bB = *(const short8*)&BsBuf[(wn * 32 + 16 + fr) * 328 + kb + g * 8];
            #pragma unroll
            for (int mf = 0; mf < 4; ++mf) {
                short8 a = *(const short8*)&h0t[wm * 64 + mf * 16 + fr][kb + g * 8];
                acc[mf][0] = __builtin_amdgcn_mfma_f32_16x16x32_bf16(a, bA, acc[mf][0], 0, 0, 0);
                acc[mf][1] = __builtin_amdgcn_mfma_f32_16x16x32_bf16(a, bB, acc[mf][1], 0, 0, 0);
            }
        }
        #pragma unroll
        for (int nf = 0; nf < 2; ++nf) {
            int col = ct * 64 + wn * 32 + nf * 16 + fr;
            float bv = b3[col];
            #pragma unroll
            for (int mf = 0; mf < 4; ++mf) {
                #pragma unroll
                for (int r = 0; r < 4; ++r) {
                    int row = rowBase + wm * 64 + mf * 16 + g * 4 + r;
                    if (row < M)
                        h1[(size_t)row * 320 + col] = f2bf(fmaxf(acc[mf][nf][r] + bv, 0.f));
                }
            }
        }
        __syncthreads();
    }
}

// ---------------- full-N bf16 MFMA GEMM: C[M,128] = A[M,K] @ Bt[128][K+8]^T ----------------
// 128x128 block, 4 waves 2x2 each 64x64, whole Bt staged once.
template <int K>
__global__ __launch_bounds__(256) void k_mgemmN(
    const unsigned short* __restrict__ A, const unsigned short* __restrict__ Bt,
    unsigned short* __restrict__ C, int M) {
    __shared__ __align__(16) short As[128][40];
    __shared__ __align__(16) short Bs[128][K + 8];
    constexpr int CH = (K + 8) / 8;
    int t = threadIdx.x;
    int rowBase = blockIdx.x * 128;
    for (int i = t; i < 128 * CH; i += 256) {
        int r = i / CH, c = i % CH;
        *(short8*)&Bs[r][c * 8] = *(const short8*)(Bt + (size_t)r * (K + 8) + c * 8);
    }
    int wid = t >> 6, lane = t & 63;
    int wm = wid >> 1, wn = wid & 1;
    int fr = lane & 15, g = lane >> 4;
    f32x4 acc[4][4] = {};
    for (int kb = 0; kb < K; kb += 32) {
        __syncthreads();   // Bs ready (first iter) / As reuse guard
        #pragma unroll
        for (int p = 0; p < 2; ++p) {
            int ci = t + 256 * p;
            int r = ci >> 2, q = ci & 3;
            int gr = rowBase + r;
            short8 v = {};
            if (gr < M) v = *(const short8*)(A + (size_t)gr * K + kb + q * 8);
            *(short8*)&As[r][q * 8] = v;
        }
        __syncthreads();
        short8 bfr[4];
        #pragma unroll
        for (int nf = 0; nf < 4; ++nf)
            bfr[nf] = *(const short8*)&Bs[wn * 64 + nf * 16 + fr][kb + g * 8];
        #pragma unroll
        for (int mf = 0; mf < 4; ++mf) {
            short8 a = *(const short8*)&As[wm * 64 + mf * 16 + fr][g * 8];
            #pragma unroll
            for (int nf = 0; nf < 4; ++nf)
                acc[mf][nf] = __builtin_amdgcn_mfma_f32_16x16x32_bf16(a, bfr[nf], acc[mf][nf], 0, 0, 0);
        }
    }
    #pragma unroll
    for (int mf = 0; mf < 4; ++mf) {
        #pragma unroll
        for (int r = 0; r < 4; ++r) {
            int row = rowBase + wm * 64 + mf * 16 + g * 4 + r;
            if (row < M) {
                #pragma unroll
                for (int nf = 0; nf < 4; ++nf) {
                    int col = wn * 64 + nf * 16 + fr;
                    C[(size_t)row * 128 + col] = f2bf(acc[mf][nf][r]);
                }
            }
        }
    }
}

// ---------------- fused gather conv (bf16): h = relu(sum hw[src]*norm + hw*dis^2 + b)
//                  + community-pool atomics; norm precomputed per edge ----------------
__global__ __launch_bounds__(256) void k_gather(
    const int* __restrict__ rowofs, const int* __restrict__ csr_src,
    const float* __restrict__ csr_norm,
    const float* __restrict__ dis, const unsigned short* __restrict__ hw,
    const float* __restrict__ bias, const int* __restrict__ comm,
    unsigned short* __restrict__ hout, float* __restrict__ sums,
    float* __restrict__ cnt, int doCnt) {
    int wid = blockIdx.x * 4 + (threadIdx.x >> 6);
    wid = __builtin_amdgcn_readfirstlane(wid);
    int lane = threadIdx.x & 63;
    if (wid >= NN) return;
    int ro = rowofs[wid], re = rowofs[wid + 1];
    int c = lane * 2;
    float dsd = dis[wid];
    float self = dsd * dsd;
    unsigned int hv = *(const unsigned int*)(hw + (size_t)wid * 128 + c);
    float a0 = bf2f(hv & 0xffffu) * self + bias[c];
    float a1 = bf2f(hv >> 16) * self + bias[c + 1];
    int e = ro;
    for (; e + 4 <= re; e += 4) {
        int s0 = csr_src[e], s1i = csr_src[e + 1];
        int s2 = csr_src[e + 2], s3 = csr_src[e + 3];
        float n0 = csr_norm[e], n1 = csr_norm[e + 1];
        float n2 = csr_norm[e + 2], n3 = csr_norm[e + 3];
        unsigned int v0 = *(const unsigned int*)(hw + (size_t)s0 * 128 + c);
        unsigned int v1 = *(const unsigned int*)(hw + (size_t)s1i * 128 + c);
        unsigned int v2 = *(const unsigned int*)(hw + (size_t)s2 * 128 + c);
        unsigned int v3 = *(const unsigned int*)(hw + (size_t)s3 * 128 + c);
        a0 += bf2f(v0 & 0xffffu) * n0 + bf2f(v1 & 0xffffu) * n1
            + bf2f(v2 & 0xffffu) * n2 + bf2f(v3 & 0xffffu) * n3;
        a1 += bf2f(v0 >> 16) * n0 + bf2f(v1 >> 16) * n1
            + bf2f(v2 >> 16) * n2 + bf2f(v3 >> 16) * n3;
    }
    for (; e < re; ++e) {
        int s0 = csr_src[e];
        float n0 = csr_norm[e];
        unsigned int v0 = *(const unsigned int*)(hw + (size_t)s0 * 128 + c);
        a0 += bf2f(v0 & 0xffffu) * n0;
        a1 += bf2f(v0 >> 16) * n0;
    }
    a0 = fmaxf(a0, 0.f);
    a1 = fmaxf(a1, 0.f);
    unsigned int packed = ((unsigned int)f2bf(a1) << 16) | f2bf(a0);
    *(unsigned int*)(hout + (size_t)wid * 128 + c) = packed;
    int cm = comm[wid];
    atomicAdd(sums + (size_t)cm * 128 + c + 0, a0);
    atomicAdd(sums + (size_t)cm * 128 + c + 1, a1);
    if (doCnt && lane == 0) atomicAdd(cnt + cm, 1.0f);
}

// ---------------- final MLP over communities (fp32) ----------------
__global__ __launch_bounds__(128) void k_final(
    const float* __restrict__ s1, const float* __restrict__ s2,
    const float* __restrict__ cnt,
    const float* __restrict__ Wl1, const float* __restrict__ bl1,
    const float* __restrict__ Wl2, const float* __restrict__ bl2,
    float* __restrict__ out) {
    __shared__ float zh[128];
    __shared__ float partial[2];
    int c = blockIdx.x, t = threadIdx.x;
    float invc = 1.0f / fmaxf(cnt[c], 1.0f);
    zh[t] = (s1[(size_t)c * 128 + t] + s2[(size_t)c * 128 + t]) * invc;
    __syncthreads();
    float acc = bl1[t];
    for (int k = 0; k < 128; ++k)
        acc += zh[k] * (Wl1[(size_t)k * 128 + t] + Wl1[(size_t)(k + 128) * 128 + t]);
    float zv = fmaxf(acc, 0.f);
    float p = zv * Wl2[t];
    #pragma unroll
    for (int off = 32; off > 0; off >>= 1) p += __shfl_down(p, off, 64);
    if ((t & 63) == 0) partial[t >> 6] = p;
    __syncthreads();
    if (t == 0) out[c] = partial[0] + partial[1] + bl2[0];
}

extern "C" void kernel_launch(void* const* d_in, const int* in_sizes, int n_in,
                              void* d_out, int out_size, void* d_ws, size_t ws_size,
                              hipStream_t stream) {
    const float* x       = (const float*)d_in[0];
    const int*   edge    = (const int*)d_in[1];
    const int*   comm    = (const int*)d_in[2];
    const float* id_emb  = (const float*)d_in[3];
    const float* W1      = (const float*)d_in[4];
    const float* b1      = (const float*)d_in[5];
    const float* W2      = (const float*)d_in[6];
    const float* b2      = (const float*)d_in[7];
    const float* W3      = (const float*)d_in[8];
    const float* b3      = (const float*)d_in[9];
    const float* Wc1     = (const float*)d_in[10];
    const float* bc1     = (const float*)d_in[11];
    const float* Wc2     = (const float*)d_in[12];
    const float* bc2     = (const float*)d_in[13];
    const float* Wl1     = (const float*)d_in[14];
    const float* bl1     = (const float*)d_in[15];
    const float* Wl2     = (const float*)d_in[16];
    const float* bl2     = (const float*)d_in[17];
    float* out = (float*)d_out;
    float* ws  = (float*)d_ws;

    const int* srcIdx = edge;
    const int* dstIdx = edge + EE;

    size_t o = 0;
    auto alloc = [&](size_t nfloats) {
        float* p = ws + o; o += (nfloats + 3) & ~(size_t)3; return p;
    };
    float* dis   = alloc(NN);
    float* cnt   = alloc(1024);
    float* s1    = alloc((size_t)CC * 128);
    float* s2    = alloc((size_t)CC * 128);
    int* rowcnt  = (int*)alloc(NN);
    int* rowofs  = (int*)alloc(NN + 8);
    int* bsum    = (int*)alloc(512);
    int* csrsrc  = (int*)alloc(EE);
    float* csrnorm = alloc(EE);
    unsigned short* W3t  = (unsigned short*)alloc(320 * 328 / 2);
    unsigned short* Wc1t = (unsigned short*)alloc(128 * 328 / 2);
    unsigned short* Wc2t = (unsigned short*)alloc(128 * 136 / 2);
    unsigned short* h1   = (unsigned short*)alloc((size_t)NN * 320 / 2);
    unsigned short* hwb  = (unsigned short*)alloc((size_t)NN * 128 / 2);
    unsigned short* h23  = (unsigned short*)alloc((size_t)NN * 128 / 2);

    // ---- CSR build + degree norm ----
    k_init<<<500, 256, 0, stream>>>(rowcnt, s1, s2, cnt);
    k_counti<<<EE / 256, 256, 0, stream>>>(dstIdx, rowcnt);
    k_dis<<<(NN + 255) / 256, 256, 0, stream>>>(rowcnt, dis);
    k_blocksum<<<NB, 256, 0, stream>>>(rowcnt, bsum);
    k_scanb<<<1, 512, 0, stream>>>(bsum);
    k_writeofs<<<NB, 256, 0, stream>>>(rowcnt, bsum, rowofs);
    k_fill<<<EE / 256, 256, 0, stream>>>(srcIdx, dstIdx, dis, rowofs, rowcnt,
                                         csrsrc, csrnorm);

    // ---- weight convert/transpose to bf16 (one launch) ----
    k_wconv<<<dim3(2, 576), 256, 0, stream>>>(W3, W3t, Wc1, Wc1t, Wc2, Wc2t);

    int rb = (NN + 127) / 128;   // 782
    // ---- fused embed + emb3 GEMM ----
    k_emb3<<<rb, 256, 0, stream>>>(x, id_emb, W1, b1, W2, b2, W3t, b3, h1, NN);
    // ---- conv1 ----
    k_mgemmN<320><<<rb, 256, 0, stream>>>(h1, Wc1t, hwb, NN);
    k_gather<<<(NN + 3) / 4, 256, 0, stream>>>(rowofs, csrsrc, csrnorm, dis, hwb,
                                               bc1, comm, h23, s1, cnt, 1);
    // ---- conv2 ----
    k_mgemmN<128><<<rb, 256, 0, stream>>>(h23, Wc2t, hwb, NN);
    k_gather<<<(NN + 3) / 4, 256, 0, stream>>>(rowofs, csrsrc, csrnorm, dis, hwb,
                                               bc2, comm, h23, s2, cnt, 0);

    // ---- final MLP ----
    k_final<<<CC, 128, 0, stream>>>(s1, s2, cnt, Wl1, bl1, Wl2, bl2, out);
}

// Round 5
// 664.724 us; speedup vs baseline: 1.1070x; 1.1070x over previous
//
#include <hip/hip_runtime.h>
#include <hip/hip_bf16.h>
#include <cstddef>

#define NN 100000
#define EE 1600000
#define CC 1000
#define NB ((NN + 255) / 256)   // 391 scan blocks

using short8 = __attribute__((ext_vector_type(8))) short;
using f32x4  = __attribute__((ext_vector_type(4))) float;

__device__ __forceinline__ float bf2f(unsigned int u) {
    union { unsigned int i; float f; } x; x.i = u << 16; return x.f;
}
__device__ __forceinline__ unsigned short f2bf(float f) {
    __hip_bfloat16 h = __float2bfloat16(f);
    return *reinterpret_cast<unsigned short*>(&h);
}

// ---------------- init: rowcnt=0, sums=0, cnt=0 ----------------
__global__ void k_init(int* __restrict__ rowcnt, float* __restrict__ s1,
                       float* __restrict__ s2, float* __restrict__ cnt) {
    int i = blockIdx.x * 256 + threadIdx.x;   // grid covers 128000
    if (i < NN) rowcnt[i] = 0;
    if (i < CC * 128) { s1[i] = 0.f; s2[i] = 0.f; }
    if (i < CC) cnt[i] = 0.f;
}

// ---------------- degree histogram over dst ----------------
__global__ void k_counti(const int* __restrict__ dst, int* __restrict__ rowcnt) {
    int i = blockIdx.x * 256 + threadIdx.x;
    if (i < EE) atomicAdd(&rowcnt[dst[i]], 1);
}

// ---------------- scan step 1: per-block sums (+ dis = rsqrt(deg+1)) ----------------
__global__ void k_blocksum(const int* __restrict__ rowcnt, int* __restrict__ bsum,
                           float* __restrict__ dis) {
    __shared__ int sd[256];
    int t = threadIdx.x, i = blockIdx.x * 256 + t;
    int v = (i < NN) ? rowcnt[i] : 0;
    sd[t] = v;
    if (i < NN) dis[i] = rsqrtf((float)v + 1.0f);
    __syncthreads();
    for (int s = 128; s > 0; s >>= 1) {
        if (t < s) sd[t] += sd[t + s];
        __syncthreads();
    }
    if (t == 0) bsum[blockIdx.x] = sd[0];
}

// ---------------- scan step 2: exclusive scan of block sums (1 block) ----------------
__global__ void k_scanb(int* __restrict__ bsum) {
    __shared__ int sd[512];
    int t = threadIdx.x;
    int v = (t < NB) ? bsum[t] : 0;
    sd[t] = v;
    __syncthreads();
    for (int off = 1; off < 512; off <<= 1) {
        int x = (t >= off) ? sd[t - off] : 0;
        __syncthreads();
        sd[t] += x;
        __syncthreads();
    }
    if (t < NB) bsum[t] = sd[t] - v;   // exclusive
}

// ---------------- scan step 3: write row offsets, zero rowcnt for reuse ----------------
__global__ void k_writeofs(int* __restrict__ rowcnt, const int* __restrict__ bsum,
                           int* __restrict__ rowofs) {
    __shared__ int sd[256];
    int t = threadIdx.x, i = blockIdx.x * 256 + t;
    int v = (i < NN) ? rowcnt[i] : 0;
    sd[t] = v;
    __syncthreads();
    for (int off = 1; off < 256; off <<= 1) {
        int x = (t >= off) ? sd[t - off] : 0;
        __syncthreads();
        sd[t] += x;
        __syncthreads();
    }
    if (i < NN) {
        rowofs[i] = bsum[blockIdx.x] + sd[t] - v;
        rowcnt[i] = 0;                 // reset for fill pass
    }
    if (i == 0) rowofs[NN] = EE;
}

// ---------------- CSR fill: csr_src + csr_norm sorted by dst ----------------
__global__ void k_fill(const int* __restrict__ src, const int* __restrict__ dst,
                       const float* __restrict__ dis,
                       const int* __restrict__ rowofs, int* __restrict__ rowcnt,
                       int* __restrict__ csr_src, float* __restrict__ csr_norm) {
    int e = blockIdx.x * 256 + threadIdx.x;
    if (e >= EE) return;
    int d = dst[e], s = src[e];
    int pos = rowofs[d] + atomicAdd(&rowcnt[d], 1);
    csr_src[pos] = s;
    csr_norm[pos] = dis[s] * dis[d];
}

// ---------------- weight convert+transpose (all 3): W[K][N] f32 -> Wt[N][K+8] bf16 ----------------
__global__ void k_wconv(const float* __restrict__ W3, unsigned short* __restrict__ W3t,
                        const float* __restrict__ Wc1, unsigned short* __restrict__ Wc1t,
                        const float* __restrict__ Wc2, unsigned short* __restrict__ Wc2t) {
    int y = blockIdx.y;
    int k = blockIdx.x * 256 + threadIdx.x;
    if (y < 320) {              // W3: K=320, N=320
        if (k < 328) W3t[(size_t)y * 328 + k] = (k < 320) ? f2bf(W3[(size_t)k * 320 + y]) : 0;
    } else if (y < 448) {       // Wc1: K=320, N=128
        int n = y - 320;
        if (k < 328) Wc1t[(size_t)n * 328 + k] = (k < 320) ? f2bf(Wc1[(size_t)k * 128 + n]) : 0;
    } else {                    // Wc2: K=128, N=128
        int n = y - 448;
        if (k < 136) Wc2t[(size_t)n * 136 + k] = (k < 128) ? f2bf(Wc2[(size_t)k * 128 + n]) : 0;
    }
}

// ---------------- embed: h0 = [relu(x[:, :7]W1+b1) | relu(x[:,7:]W2+b2) | id], bf16 ----------------
__global__ __launch_bounds__(256) void k_embed(
    const float* __restrict__ x, const float* __restrict__ id_emb,
    const float* __restrict__ W1, const float* __restrict__ b1,
    const float* __restrict__ W2, const float* __restrict__ b2,
    unsigned short* __restrict__ h0) {
    __shared__ float W1s[7 * 128];
    __shared__ float W2s[12 * 128];
    __shared__ float b1s[128], b2s[128];
    __shared__ float xs[4][20];
    int t = threadIdx.x;
    for (int i = t; i < 7 * 128; i += 256) W1s[i] = W1[i];
    for (int i = t; i < 12 * 128; i += 256) W2s[i] = W2[i];
    if (t < 128) { b1s[t] = b1[t]; b2s[t] = b2[t]; }
    int ln = t >> 6, lane = t & 63;
    int node = blockIdx.x * 4 + ln;
    if (node < NN && lane < 19) xs[ln][lane] = x[(size_t)node * 19 + lane];
    __syncthreads();
    if (node >= NN) return;
    #pragma unroll
    for (int c5 = 0; c5 < 5; ++c5) {
        int c = lane + 64 * c5;
        float v;
        if (c < 128) {
            float acc = b1s[c];
            #pragma unroll
            for (int k = 0; k < 7; ++k) acc += xs[ln][k] * W1s[k * 128 + c];
            v = fmaxf(acc, 0.f);
        } else if (c < 256) {
            int cc = c - 128;
            float acc = b2s[cc];
            #pragma unroll
            for (int k = 0; k < 12; ++k) acc += xs[ln][7 + k] * W2s[k * 128 + cc];
            v = fmaxf(acc, 0.f);
        } else {
            v = id_emb[(size_t)node * 64 + (c - 256)];
        }
        h0[(size_t)node * 320 + c] = f2bf(v);
    }
}

// ---------------- bf16 MFMA GEMM, 64-col tiles: C = relu(A@B + bias) ----------------
// 128x64 tile, 4 waves (2x2), wave tile 64x32 = 4x2 frags of 16x16, fp32 acc.
template <int K, int N, int RELU>
__global__ __launch_bounds__(256) void k_mgemm5(
    const unsigned short* __restrict__ A, const unsigned short* __restrict__ Bt,
    const float* __restrict__ bias, unsigned short* __restrict__ C, int M) {
    __shared__ __align__(16) short As[128][40];        // BK=32, +8 pad
    __shared__ __align__(16) short Bs[64][K + 8];
    constexpr int CH = (K + 8) / 8;
    int t = threadIdx.x;
    int rowBase = blockIdx.x * 128;
    int colBase = blockIdx.y * 64;
    for (int idx = t; idx < 64 * CH; idx += 256) {
        int r = idx / CH, c = idx % CH;
        *(short8*)&Bs[r][c * 8] =
            *(const short8*)(Bt + (size_t)(colBase + r) * (K + 8) + c * 8);
    }
    int wid = t >> 6, lane = t & 63;
    int wm = wid >> 1, wn = wid & 1;
    int fr = lane & 15, g = lane >> 4;
    f32x4 acc[4][2] = {};
    for (int kb = 0; kb < K; kb += 32) {
        __syncthreads();     // As reuse guard (also covers initial Bs stage)
        #pragma unroll
        for (int p = 0; p < 2; ++p) {
            int ci = t + 256 * p;
            int r = ci >> 2, q = ci & 3;
            int grow = rowBase + r;
            short8 v = {};
            if (grow < M) v = *(const short8*)(A + (size_t)grow * K + kb + q * 8);
            *(short8*)&As[r][q * 8] = v;
        }
        __syncthreads();
        short8 b0 = *(const short8*)&Bs[wn * 32 + fr][kb + g * 8];
        short8 b1 = *(const short8*)&Bs[wn * 32 + 16 + fr][kb + g * 8];
        #pragma unroll
        for (int mf = 0; mf < 4; ++mf) {
            short8 a = *(const short8*)&As[wm * 64 + mf * 16 + fr][g * 8];
            acc[mf][0] = __builtin_amdgcn_mfma_f32_16x16x32_bf16(a, b0, acc[mf][0], 0, 0, 0);
            acc[mf][1] = __builtin_amdgcn_mfma_f32_16x16x32_bf16(a, b1, acc[mf][1], 0, 0, 0);
        }
    }
    #pragma unroll
    for (int nf = 0; nf < 2; ++nf) {
        int col = colBase + wn * 32 + nf * 16 + fr;
        float bv = RELU ? bias[col] : 0.f;
        #pragma unroll
        for (int mf = 0; mf < 4; ++mf) {
            #pragma unroll
            for (int r = 0; r < 4; ++r) {
                int row = rowBase + wm * 64 + mf * 16 + g * 4 + r;
                if (row < M) {
                    float v = acc[mf][nf][r];
                    if (RELU) v = fmaxf(v + bv, 0.f);
                    C[(size_t)row * N + col] = f2bf(v);
                }
            }
        }
    }
}

// ---------------- full-N bf16 MFMA GEMM: C[M,128] = A[M,K] @ Bt[128][K+8]^T ----------------
template <int K>
__global__ __launch_bounds__(256) void k_mgemmN(
    const unsigned short* __restrict__ A, const unsigned short* __restrict__ Bt,
    unsigned short* __restrict__ C, int M) {
    __shared__ __align__(16) short As[128][40];
    __shared__ __align__(16) short Bs[128][K + 8];
    constexpr int CH = (K + 8) / 8;
    int t = threadIdx.x;
    int rowBase = blockIdx.x * 128;
    for (int i = t; i < 128 * CH; i += 256) {
        int r = i / CH, c = i % CH;
        *(short8*)&Bs[r][c * 8] = *(const short8*)(Bt + (size_t)r * (K + 8) + c * 8);
    }
    int wid = t >> 6, lane = t & 63;
    int wm = wid >> 1, wn = wid & 1;
    int fr = lane & 15, g = lane >> 4;
    f32x4 acc[4][4] = {};
    for (int kb = 0; kb < K; kb += 32) {
        __syncthreads();   // Bs ready (first iter) / As reuse guard
        #pragma unroll
        for (int p = 0; p < 2; ++p) {
            int ci = t + 256 * p;
            int r = ci >> 2, q = ci & 3;
            int gr = rowBase + r;
            short8 v = {};
            if (gr < M) v = *(const short8*)(A + (size_t)gr * K + kb + q * 8);
            *(short8*)&As[r][q * 8] = v;
        }
        __syncthreads();
        short8 bfr[4];
        #pragma unroll
        for (int nf = 0; nf < 4; ++nf)
            bfr[nf] = *(const short8*)&Bs[wn * 64 + nf * 16 + fr][kb + g * 8];
        #pragma unroll
        for (int mf = 0; mf < 4; ++mf) {
            short8 a = *(const short8*)&As[wm * 64 + mf * 16 + fr][g * 8];
            #pragma unroll
            for (int nf = 0; nf < 4; ++nf)
                acc[mf][nf] = __builtin_amdgcn_mfma_f32_16x16x32_bf16(a, bfr[nf], acc[mf][nf], 0, 0, 0);
        }
    }
    #pragma unroll
    for (int mf = 0; mf < 4; ++mf) {
        #pragma unroll
        for (int r = 0; r < 4; ++r) {
            int row = rowBase + wm * 64 + mf * 16 + g * 4 + r;
            if (row < M) {
                #pragma unroll
                for (int nf = 0; nf < 4; ++nf) {
                    int col = wn * 64 + nf * 16 + fr;
                    C[(size_t)row * 128 + col] = f2bf(acc[mf][nf][r]);
                }
            }
        }
    }
}

// ---------------- fused gather conv (bf16): h = relu(sum hw[src]*norm + hw*dis^2 + b)
//                  + community-pool atomics; unroll 8 for MLP ----------------
__global__ __launch_bounds__(256) void k_gather(
    const int* __restrict__ rowofs, const int* __restrict__ csr_src,
    const float* __restrict__ csr_norm,
    const float* __restrict__ dis, const unsigned short* __restrict__ hw,
    const float* __restrict__ bias, const int* __restrict__ comm,
    unsigned short* __restrict__ hout, float* __restrict__ sums,
    float* __restrict__ cnt, int doCnt) {
    int wid = blockIdx.x * 4 + (threadIdx.x >> 6);
    wid = __builtin_amdgcn_readfirstlane(wid);
    int lane = threadIdx.x & 63;
    if (wid >= NN) return;
    int ro = rowofs[wid], re = rowofs[wid + 1];
    int c = lane * 2;
    float dsd = dis[wid];
    float self = dsd * dsd;
    unsigned int hv = *(const unsigned int*)(hw + (size_t)wid * 128 + c);
    float a0 = bf2f(hv & 0xffffu) * self + bias[c];
    float a1 = bf2f(hv >> 16) * self + bias[c + 1];
    int e = ro;
    for (; e + 8 <= re; e += 8) {
        int s[8]; float n[8]; unsigned int v[8];
        #pragma unroll
        for (int j = 0; j < 8; ++j) { s[j] = csr_src[e + j]; n[j] = csr_norm[e + j]; }
        #pragma unroll
        for (int j = 0; j < 8; ++j)
            v[j] = *(const unsigned int*)(hw + (size_t)s[j] * 128 + c);
        #pragma unroll
        for (int j = 0; j < 8; ++j) {
            a0 += bf2f(v[j] & 0xffffu) * n[j];
            a1 += bf2f(v[j] >> 16) * n[j];
        }
    }
    for (; e + 2 <= re; e += 2) {
        int s0 = csr_src[e], s1i = csr_src[e + 1];
        float n0 = csr_norm[e], n1 = csr_norm[e + 1];
        unsigned int v0 = *(const unsigned int*)(hw + (size_t)s0 * 128 + c);
        unsigned int v1 = *(const unsigned int*)(hw + (size_t)s1i * 128 + c);
        a0 += bf2f(v0 & 0xffffu) * n0 + bf2f(v1 & 0xffffu) * n1;
        a1 += bf2f(v0 >> 16) * n0 + bf2f(v1 >> 16) * n1;
    }
    if (e < re) {
        int s0 = csr_src[e];
        float n0 = csr_norm[e];
        unsigned int v0 = *(const unsigned int*)(hw + (size_t)s0 * 128 + c);
        a0 += bf2f(v0 & 0xffffu) * n0;
        a1 += bf2f(v0 >> 16) * n0;
    }
    a0 = fmaxf(a0, 0.f);
    a1 = fmaxf(a1, 0.f);
    unsigned int packed = ((unsigned int)f2bf(a1) << 16) | f2bf(a0);
    *(unsigned int*)(hout + (size_t)wid * 128 + c) = packed;
    int cm = comm[wid];
    atomicAdd(sums + (size_t)cm * 128 + c + 0, a0);
    atomicAdd(sums + (size_t)cm * 128 + c + 1, a1);
    if (doCnt && lane == 0) atomicAdd(cnt + cm, 1.0f);
}

// ---------------- final MLP over communities (fp32) ----------------
__global__ __launch_bounds__(128) void k_final(
    const float* __restrict__ s1, const float* __restrict__ s2,
    const float* __restrict__ cnt,
    const float* __restrict__ Wl1, const float* __restrict__ bl1,
    const float* __restrict__ Wl2, const float* __restrict__ bl2,
    float* __restrict__ out) {
    __shared__ float zh[128];
    __shared__ float partial[2];
    int c = blockIdx.x, t = threadIdx.x;
    float invc = 1.0f / fmaxf(cnt[c], 1.0f);
    zh[t] = (s1[(size_t)c * 128 + t] + s2[(size_t)c * 128 + t]) * invc;
    __syncthreads();
    float acc = bl1[t];
    for (int k = 0; k < 128; ++k)
        acc += zh[k] * (Wl1[(size_t)k * 128 + t] + Wl1[(size_t)(k + 128) * 128 + t]);
    float zv = fmaxf(acc, 0.f);
    float p = zv * Wl2[t];
    #pragma unroll
    for (int off = 32; off > 0; off >>= 1) p += __shfl_down(p, off, 64);
    if ((t & 63) == 0) partial[t >> 6] = p;
    __syncthreads();
    if (t == 0) out[c] = partial[0] + partial[1] + bl2[0];
}

extern "C" void kernel_launch(void* const* d_in, const int* in_sizes, int n_in,
                              void* d_out, int out_size, void* d_ws, size_t ws_size,
                              hipStream_t stream) {
    const float* x       = (const float*)d_in[0];
    const int*   edge    = (const int*)d_in[1];
    const int*   comm    = (const int*)d_in[2];
    const float* id_emb  = (const float*)d_in[3];
    const float* W1      = (const float*)d_in[4];
    const float* b1      = (const float*)d_in[5];
    const float* W2      = (const float*)d_in[6];
    const float* b2      = (const float*)d_in[7];
    const float* W3      = (const float*)d_in[8];
    const float* b3      = (const float*)d_in[9];
    const float* Wc1     = (const float*)d_in[10];
    const float* bc1     = (const float*)d_in[11];
    const float* Wc2     = (const float*)d_in[12];
    const float* bc2     = (const float*)d_in[13];
    const float* Wl1     = (const float*)d_in[14];
    const float* bl1     = (const float*)d_in[15];
    const float* Wl2     = (const float*)d_in[16];
    const float* bl2     = (const float*)d_in[17];
    float* out = (float*)d_out;
    float* ws  = (float*)d_ws;

    const int* srcIdx = edge;
    const int* dstIdx = edge + EE;

    size_t o = 0;
    auto alloc = [&](size_t nfloats) {
        float* p = ws + o; o += (nfloats + 3) & ~(size_t)3; return p;
    };
    float* dis   = alloc(NN);
    float* cnt   = alloc(1024);
    float* s1    = alloc((size_t)CC * 128);
    float* s2    = alloc((size_t)CC * 128);
    int* rowcnt  = (int*)alloc(NN);
    int* rowofs  = (int*)alloc(NN + 8);
    int* bsum    = (int*)alloc(512);
    int* csrsrc  = (int*)alloc(EE);
    float* csrnorm = alloc(EE);
    unsigned short* W3t  = (unsigned short*)alloc(320 * 328 / 2);
    unsigned short* Wc1t = (unsigned short*)alloc(128 * 328 / 2);
    unsigned short* Wc2t = (unsigned short*)alloc(128 * 136 / 2);
    unsigned short* h0   = (unsigned short*)alloc((size_t)NN * 320 / 2);
    unsigned short* h1   = (unsigned short*)alloc((size_t)NN * 320 / 2);
    unsigned short* hwb  = (unsigned short*)alloc((size_t)NN * 128 / 2);
    unsigned short* h23  = (unsigned short*)alloc((size_t)NN * 128 / 2);

    // ---- CSR build + degree norm ----
    k_init<<<500, 256, 0, stream>>>(rowcnt, s1, s2, cnt);
    k_counti<<<EE / 256, 256, 0, stream>>>(dstIdx, rowcnt);
    k_blocksum<<<NB, 256, 0, stream>>>(rowcnt, bsum, dis);
    k_scanb<<<1, 512, 0, stream>>>(bsum);
    k_writeofs<<<NB, 256, 0, stream>>>(rowcnt, bsum, rowofs);
    k_fill<<<EE / 256, 256, 0, stream>>>(srcIdx, dstIdx, dis, rowofs, rowcnt,
                                         csrsrc, csrnorm);

    // ---- weight convert/transpose to bf16 (one launch) ----
    k_wconv<<<dim3(2, 576), 256, 0, stream>>>(W3, W3t, Wc1, Wc1t, Wc2, Wc2t);

    // ---- embedding (bf16 out) ----
    k_embed<<<(NN + 3) / 4, 256, 0, stream>>>(x, id_emb, W1, b1, W2, b2, h0);

    int rb = (NN + 127) / 128;   // 782
    // h1 = relu(h0 @ W3 + b3)
    k_mgemm5<320, 320, 1><<<dim3(rb, 5), 256, 0, stream>>>(h0, W3t, b3, h1, NN);
    // ---- conv1 ----
    k_mgemmN<320><<<rb, 256, 0, stream>>>(h1, Wc1t, hwb, NN);
    k_gather<<<(NN + 3) / 4, 256, 0, stream>>>(rowofs, csrsrc, csrnorm, dis, hwb,
                                               bc1, comm, h23, s1, cnt, 1);
    // ---- conv2 ----
    k_mgemmN<128><<<rb, 256, 0, stream>>>(h23, Wc2t, hwb, NN);
    k_gather<<<(NN + 3) / 4, 256, 0, stream>>>(rowofs, csrsrc, csrnorm, dis, hwb,
                                               bc2, comm, h23, s2, cnt, 0);

    // ---- final MLP ----
    k_final<<<CC, 128, 0, stream>>>(s1, s2, cnt, Wl1, bl1, Wl2, bl2, out);
}

// Round 6
// 622.960 us; speedup vs baseline: 1.1812x; 1.0670x over previous
//
#include <hip/hip_runtime.h>
#include <hip/hip_bf16.h>
#include <cstddef>

#define NN 100000
#define EE 1600000
#define CC 1000
#define NB ((NN + 255) / 256)   // 391 scan blocks

using short8 = __attribute__((ext_vector_type(8))) short;
using f32x4  = __attribute__((ext_vector_type(4))) float;

__device__ __forceinline__ float bf2f(unsigned int u) {
    union { unsigned int i; float f; } x; x.i = u << 16; return x.f;
}
__device__ __forceinline__ unsigned short f2bf(float f) {
    __hip_bfloat16 h = __float2bfloat16(f);
    return *reinterpret_cast<unsigned short*>(&h);
}
__device__ __forceinline__ unsigned int pack2(float lo, float hi) {
    return ((unsigned int)f2bf(hi) << 16) | f2bf(lo);
}

// ---------------- init: rowcnt=0, sums=0, cnt=0 ----------------
__global__ void k_init(int* __restrict__ rowcnt, float* __restrict__ s1,
                       float* __restrict__ s2, float* __restrict__ cnt) {
    int i = blockIdx.x * 256 + threadIdx.x;   // grid covers 128000
    if (i < NN) rowcnt[i] = 0;
    if (i < CC * 128) { s1[i] = 0.f; s2[i] = 0.f; }
    if (i < CC) cnt[i] = 0.f;
}

// ---------------- degree histogram over dst ----------------
__global__ void k_counti(const int* __restrict__ dst, int* __restrict__ rowcnt) {
    int i = blockIdx.x * 256 + threadIdx.x;
    if (i < EE) atomicAdd(&rowcnt[dst[i]], 1);
}

// ---------------- scan step 1: per-block sums (+ dis = rsqrt(deg+1)) ----------------
__global__ void k_blocksum(const int* __restrict__ rowcnt, int* __restrict__ bsum,
                           float* __restrict__ dis) {
    __shared__ int sd[256];
    int t = threadIdx.x, i = blockIdx.x * 256 + t;
    int v = (i < NN) ? rowcnt[i] : 0;
    sd[t] = v;
    if (i < NN) dis[i] = rsqrtf((float)v + 1.0f);
    __syncthreads();
    for (int s = 128; s > 0; s >>= 1) {
        if (t < s) sd[t] += sd[t + s];
        __syncthreads();
    }
    if (t == 0) bsum[blockIdx.x] = sd[0];
}

// ---------------- scan step 2: exclusive scan of block sums (1 block) ----------------
__global__ void k_scanb(int* __restrict__ bsum) {
    __shared__ int sd[512];
    int t = threadIdx.x;
    int v = (t < NB) ? bsum[t] : 0;
    sd[t] = v;
    __syncthreads();
    for (int off = 1; off < 512; off <<= 1) {
        int x = (t >= off) ? sd[t - off] : 0;
        __syncthreads();
        sd[t] += x;
        __syncthreads();
    }
    if (t < NB) bsum[t] = sd[t] - v;   // exclusive
}

// ---------------- scan step 3: write row offsets, zero rowcnt for reuse ----------------
__global__ void k_writeofs(int* __restrict__ rowcnt, const int* __restrict__ bsum,
                           int* __restrict__ rowofs) {
    __shared__ int sd[256];
    int t = threadIdx.x, i = blockIdx.x * 256 + t;
    int v = (i < NN) ? rowcnt[i] : 0;
    sd[t] = v;
    __syncthreads();
    for (int off = 1; off < 256; off <<= 1) {
        int x = (t >= off) ? sd[t - off] : 0;
        __syncthreads();
        sd[t] += x;
        __syncthreads();
    }
    if (i < NN) {
        rowofs[i] = bsum[blockIdx.x] + sd[t] - v;
        rowcnt[i] = 0;                 // reset for fill pass
    }
    if (i == 0) rowofs[NN] = EE;
}

// ---------------- CSR fill: packed {src, norm} sorted by dst ----------------
__global__ void k_fill(const int* __restrict__ src, const int* __restrict__ dst,
                       const float* __restrict__ dis,
                       const int* __restrict__ rowofs, int* __restrict__ rowcnt,
                       int2* __restrict__ csr) {
    int e = blockIdx.x * 256 + threadIdx.x;
    if (e >= EE) return;
    int d = dst[e], s = src[e];
    int pos = rowofs[d] + atomicAdd(&rowcnt[d], 1);
    csr[pos] = make_int2(s, __float_as_int(dis[s] * dis[d]));
}

// ---------------- weight convert+transpose (all 3): W[K][N] f32 -> Wt[N][K+8] bf16 ----------------
__global__ void k_wconv(const float* __restrict__ W3, unsigned short* __restrict__ W3t,
                        const float* __restrict__ Wc1, unsigned short* __restrict__ Wc1t,
                        const float* __restrict__ Wc2, unsigned short* __restrict__ Wc2t) {
    int y = blockIdx.y;
    int k = blockIdx.x * 256 + threadIdx.x;
    if (y < 320) {              // W3: K=320, N=320
        if (k < 328) W3t[(size_t)y * 328 + k] = (k < 320) ? f2bf(W3[(size_t)k * 320 + y]) : 0;
    } else if (y < 448) {       // Wc1: K=320, N=128
        int n = y - 320;
        if (k < 328) Wc1t[(size_t)n * 328 + k] = (k < 320) ? f2bf(Wc1[(size_t)k * 128 + n]) : 0;
    } else {                    // Wc2: K=128, N=128
        int n = y - 448;
        if (k < 136) Wc2t[(size_t)n * 136 + k] = (k < 128) ? f2bf(Wc2[(size_t)k * 128 + n]) : 0;
    }
}

// ---------------- embed: h0 = [relu(x[:, :7]W1+b1) | relu(x[:,7:]W2+b2) | id], bf16 ----------------
// Each lane produces 2 adjacent cols -> packed uint stores.
__global__ __launch_bounds__(256) void k_embed(
    const float* __restrict__ x, const float* __restrict__ id_emb,
    const float* __restrict__ W1, const float* __restrict__ b1,
    const float* __restrict__ W2, const float* __restrict__ b2,
    unsigned short* __restrict__ h0) {
    __shared__ float W1s[7][128];
    __shared__ float W2s[12][128];
    __shared__ float b1s[128], b2s[128];
    __shared__ float xs[4][20];
    int t = threadIdx.x;
    for (int i = t; i < 7 * 128; i += 256) ((float*)W1s)[i] = W1[i];
    for (int i = t; i < 12 * 128; i += 256) ((float*)W2s)[i] = W2[i];
    if (t < 128) { b1s[t] = b1[t]; b2s[t] = b2[t]; }
    int ln = t >> 6, lane = t & 63;
    int node = blockIdx.x * 4 + ln;
    if (node < NN && lane < 19) xs[ln][lane] = x[(size_t)node * 19 + lane];
    __syncthreads();
    if (node >= NN) return;
    unsigned int* orow = (unsigned int*)(h0 + (size_t)node * 320);
    int c2 = lane * 2;
    // x1 pair (cols c2, c2+1)
    float a0 = b1s[c2], a1 = b1s[c2 + 1];
    #pragma unroll
    for (int k = 0; k < 7; ++k) {
        float xv = xs[ln][k];
        float2 w = *(const float2*)&W1s[k][c2];
        a0 += xv * w.x; a1 += xv * w.y;
    }
    orow[lane] = pack2(fmaxf(a0, 0.f), fmaxf(a1, 0.f));
    // x2 pair
    a0 = b2s[c2]; a1 = b2s[c2 + 1];
    #pragma unroll
    for (int k = 0; k < 12; ++k) {
        float xv = xs[ln][7 + k];
        float2 w = *(const float2*)&W2s[k][c2];
        a0 += xv * w.x; a1 += xv * w.y;
    }
    orow[64 + lane] = pack2(fmaxf(a0, 0.f), fmaxf(a1, 0.f));
    // id pair (64 cols -> 32 uints)
    if (lane < 32) {
        float2 iv = *(const float2*)(id_emb + (size_t)node * 64 + c2);
        orow[128 + lane] = pack2(iv.x, iv.y);
    }
}

// ---------------- unified bf16 MFMA GEMM, K-chunked A&B staging ----------------
// C[M,N] = [relu](A[M,K] @ Bt[N][K+8]^T [+bias]).  128x128 tile, 4 waves 2x2,
// each 64x64 (4x4 frags).  LDS 20 KB.  Grid: rb*NT blocks, ct fastest.
template <int K, int N, int RELU>
__global__ __launch_bounds__(256) void k_bgemm(
    const unsigned short* __restrict__ A, const unsigned short* __restrict__ Bt,
    const float* __restrict__ bias, unsigned short* __restrict__ C, int M) {
    constexpr int NT = (N + 127) / 128;
    __shared__ __align__(16) short As[128][40];
    __shared__ __align__(16) short Bs[128][40];
    int t = threadIdx.x;
    int bid = blockIdx.x;
    int ct = bid % NT, rblk = bid / NT;
    int rowBase = rblk * 128, colBase = ct * 128;
    int wid = t >> 6, lane = t & 63;
    int wm = wid >> 1, wn = wid & 1;
    int fr = lane & 15, g = lane >> 4;
    f32x4 acc[4][4] = {};
    for (int kb = 0; kb < K; kb += 32) {
        __syncthreads();   // LDS reuse guard
        #pragma unroll
        for (int p = 0; p < 2; ++p) {
            int ci = t + 256 * p;
            int r = ci >> 2, q = ci & 3;
            int gr = rowBase + r;
            short8 v = {};
            if (gr < M) v = *(const short8*)(A + (size_t)gr * K + kb + q * 8);
            *(short8*)&As[r][q * 8] = v;
        }
        #pragma unroll
        for (int p = 0; p < 2; ++p) {
            int ci = t + 256 * p;
            int r = ci >> 2, q = ci & 3;
            int gc = colBase + r;
            short8 v = {};
            if (gc < N) v = *(const short8*)(Bt + (size_t)gc * (K + 8) + kb + q * 8);
            *(short8*)&Bs[r][q * 8] = v;
        }
        __syncthreads();
        short8 bfr[4];
        #pragma unroll
        for (int nf = 0; nf < 4; ++nf)
            bfr[nf] = *(const short8*)&Bs[wn * 64 + nf * 16 + fr][g * 8];
        #pragma unroll
        for (int mf = 0; mf < 4; ++mf) {
            short8 a = *(const short8*)&As[wm * 64 + mf * 16 + fr][g * 8];
            #pragma unroll
            for (int nf = 0; nf < 4; ++nf)
                acc[mf][nf] = __builtin_amdgcn_mfma_f32_16x16x32_bf16(a, bfr[nf], acc[mf][nf], 0, 0, 0);
        }
    }
    #pragma unroll
    for (int nf = 0; nf < 4; ++nf) {
        int col = colBase + wn * 64 + nf * 16 + fr;
        if (col < N) {
            float bv = RELU ? bias[col] : 0.f;
            #pragma unroll
            for (int mf = 0; mf < 4; ++mf) {
                #pragma unroll
                for (int r = 0; r < 4; ++r) {
                    int row = rowBase + wm * 64 + mf * 16 + g * 4 + r;
                    if (row < M) {
                        float v = acc[mf][nf][r];
                        if (RELU) v = fmaxf(v + bv, 0.f);
                        C[(size_t)row * N + col] = f2bf(v);
                    }
                }
            }
        }
    }
}

// ---------------- fused gather conv (bf16): h = relu(sum hw[src]*norm + hw*dis^2 + b)
//                  + community-pool atomics; packed csr, unroll 16 ----------------
__global__ __launch_bounds__(256) void k_gather(
    const int* __restrict__ rowofs, const int2* __restrict__ csr,
    const float* __restrict__ dis, const unsigned short* __restrict__ hw,
    const float* __restrict__ bias, const int* __restrict__ comm,
    unsigned short* __restrict__ hout, float* __restrict__ sums,
    float* __restrict__ cnt, int doCnt) {
    int wid = blockIdx.x * 4 + (threadIdx.x >> 6);
    wid = __builtin_amdgcn_readfirstlane(wid);
    int lane = threadIdx.x & 63;
    if (wid >= NN) return;
    int ro = rowofs[wid], re = rowofs[wid + 1];
    int c = lane * 2;
    float dsd = dis[wid];
    float self = dsd * dsd;
    unsigned int hv = *(const unsigned int*)(hw + (size_t)wid * 128 + c);
    float a0 = bf2f(hv & 0xffffu) * self + bias[c];
    float a1 = bf2f(hv >> 16) * self + bias[c + 1];
    int e = ro;
    for (; e + 16 <= re; e += 16) {
        int2 pk[16]; unsigned int v[16];
        #pragma unroll
        for (int j = 0; j < 16; ++j) pk[j] = csr[e + j];
        #pragma unroll
        for (int j = 0; j < 16; ++j)
            v[j] = *(const unsigned int*)(hw + (size_t)pk[j].x * 128 + c);
        #pragma unroll
        for (int j = 0; j < 16; ++j) {
            float n = __int_as_float(pk[j].y);
            a0 += bf2f(v[j] & 0xffffu) * n;
            a1 += bf2f(v[j] >> 16) * n;
        }
    }
    for (; e + 4 <= re; e += 4) {
        int2 pk[4]; unsigned int v[4];
        #pragma unroll
        for (int j = 0; j < 4; ++j) pk[j] = csr[e + j];
        #pragma unroll
        for (int j = 0; j < 4; ++j)
            v[j] = *(const unsigned int*)(hw + (size_t)pk[j].x * 128 + c);
        #pragma unroll
        for (int j = 0; j < 4; ++j) {
            float n = __int_as_float(pk[j].y);
            a0 += bf2f(v[j] & 0xffffu) * n;
            a1 += bf2f(v[j] >> 16) * n;
        }
    }
    for (; e < re; ++e) {
        int2 pk = csr[e];
        float n = __int_as_float(pk.y);
        unsigned int v0 = *(const unsigned int*)(hw + (size_t)pk.x * 128 + c);
        a0 += bf2f(v0 & 0xffffu) * n;
        a1 += bf2f(v0 >> 16) * n;
    }
    a0 = fmaxf(a0, 0.f);
    a1 = fmaxf(a1, 0.f);
    *(unsigned int*)(hout + (size_t)wid * 128 + c) = pack2(a0, a1);
    int cm = comm[wid];
    atomicAdd(sums + (size_t)cm * 128 + c + 0, a0);
    atomicAdd(sums + (size_t)cm * 128 + c + 1, a1);
    if (doCnt && lane == 0) atomicAdd(cnt + cm, 1.0f);
}

// ---------------- final MLP over communities (fp32) ----------------
__global__ __launch_bounds__(128) void k_final(
    const float* __restrict__ s1, const float* __restrict__ s2,
    const float* __restrict__ cnt,
    const float* __restrict__ Wl1, const float* __restrict__ bl1,
    const float* __restrict__ Wl2, const float* __restrict__ bl2,
    float* __restrict__ out) {
    __shared__ float zh[128];
    __shared__ float partial[2];
    int c = blockIdx.x, t = threadIdx.x;
    float invc = 1.0f / fmaxf(cnt[c], 1.0f);
    zh[t] = (s1[(size_t)c * 128 + t] + s2[(size_t)c * 128 + t]) * invc;
    __syncthreads();
    float acc = bl1[t];
    for (int k = 0; k < 128; ++k)
        acc += zh[k] * (Wl1[(size_t)k * 128 + t] + Wl1[(size_t)(k + 128) * 128 + t]);
    float zv = fmaxf(acc, 0.f);
    float p = zv * Wl2[t];
    #pragma unroll
    for (int off = 32; off > 0; off >>= 1) p += __shfl_down(p, off, 64);
    if ((t & 63) == 0) partial[t >> 6] = p;
    __syncthreads();
    if (t == 0) out[c] = partial[0] + partial[1] + bl2[0];
}

extern "C" void kernel_launch(void* const* d_in, const int* in_sizes, int n_in,
                              void* d_out, int out_size, void* d_ws, size_t ws_size,
                              hipStream_t stream) {
    const float* x       = (const float*)d_in[0];
    const int*   edge    = (const int*)d_in[1];
    const int*   comm    = (const int*)d_in[2];
    const float* id_emb  = (const float*)d_in[3];
    const float* W1      = (const float*)d_in[4];
    const float* b1      = (const float*)d_in[5];
    const float* W2      = (const float*)d_in[6];
    const float* b2      = (const float*)d_in[7];
    const float* W3      = (const float*)d_in[8];
    const float* b3      = (const float*)d_in[9];
    const float* Wc1     = (const float*)d_in[10];
    const float* bc1     = (const float*)d_in[11];
    const float* Wc2     = (const float*)d_in[12];
    const float* bc2     = (const float*)d_in[13];
    const float* Wl1     = (const float*)d_in[14];
    const float* bl1     = (const float*)d_in[15];
    const float* Wl2     = (const float*)d_in[16];
    const float* bl2     = (const float*)d_in[17];
    float* out = (float*)d_out;
    float* ws  = (float*)d_ws;

    const int* srcIdx = edge;
    const int* dstIdx = edge + EE;

    size_t o = 0;
    auto alloc = [&](size_t nfloats) {
        float* p = ws + o; o += (nfloats + 3) & ~(size_t)3; return p;
    };
    float* dis   = alloc(NN);
    float* cnt   = alloc(1024);
    float* s1    = alloc((size_t)CC * 128);
    float* s2    = alloc((size_t)CC * 128);
    int* rowcnt  = (int*)alloc(NN);
    int* rowofs  = (int*)alloc(NN + 8);
    int* bsum    = (int*)alloc(512);
    int2* csr    = (int2*)alloc((size_t)EE * 2);
    unsigned short* W3t  = (unsigned short*)alloc(320 * 328 / 2);
    unsigned short* Wc1t = (unsigned short*)alloc(128 * 328 / 2);
    unsigned short* Wc2t = (unsigned short*)alloc(128 * 136 / 2);
    unsigned short* h0   = (unsigned short*)alloc((size_t)NN * 320 / 2);
    unsigned short* h1   = (unsigned short*)alloc((size_t)NN * 320 / 2);
    unsigned short* hwb  = (unsigned short*)alloc((size_t)NN * 128 / 2);
    unsigned short* h23  = (unsigned short*)alloc((size_t)NN * 128 / 2);

    // ---- CSR build + degree norm ----
    k_init<<<500, 256, 0, stream>>>(rowcnt, s1, s2, cnt);
    k_counti<<<EE / 256, 256, 0, stream>>>(dstIdx, rowcnt);
    k_blocksum<<<NB, 256, 0, stream>>>(rowcnt, bsum, dis);
    k_scanb<<<1, 512, 0, stream>>>(bsum);
    k_writeofs<<<NB, 256, 0, stream>>>(rowcnt, bsum, rowofs);
    k_fill<<<EE / 256, 256, 0, stream>>>(srcIdx, dstIdx, dis, rowofs, rowcnt, csr);

    // ---- weight convert/transpose to bf16 (one launch) ----
    k_wconv<<<dim3(2, 576), 256, 0, stream>>>(W3, W3t, Wc1, Wc1t, Wc2, Wc2t);

    // ---- embedding (bf16 out) ----
    k_embed<<<(NN + 3) / 4, 256, 0, stream>>>(x, id_emb, W1, b1, W2, b2, h0);

    int rb = (NN + 127) / 128;   // 782
    // h1 = relu(h0 @ W3 + b3)   (3 col-tiles, ct fastest for A locality)
    k_bgemm<320, 320, 1><<<rb * 3, 256, 0, stream>>>(h0, W3t, b3, h1, NN);
    // ---- conv1 ----
    k_bgemm<320, 128, 0><<<rb, 256, 0, stream>>>(h1, Wc1t, nullptr, hwb, NN);
    k_gather<<<(NN + 3) / 4, 256, 0, stream>>>(rowofs, csr, dis, hwb,
                                               bc1, comm, h23, s1, cnt, 1);
    // ---- conv2 ----
    k_bgemm<128, 128, 0><<<rb, 256, 0, stream>>>(h23, Wc2t, nullptr, hwb, NN);
    k_gather<<<(NN + 3) / 4, 256, 0, stream>>>(rowofs, csr, dis, hwb,
                                               bc2, comm, h23, s2, cnt, 0);

    // ---- final MLP ----
    k_final<<<CC, 128, 0, stream>>>(s1, s2, cnt, Wl1, bl1, Wl2, bl2, out);
}

// Round 7
// 596.998 us; speedup vs baseline: 1.2326x; 1.0435x over previous
//
#include <hip/hip_runtime.h>
#include <hip/hip_bf16.h>
#include <cstddef>

#define NN 100000
#define EE 1600000
#define CC 1000
#define NB ((NN + 255) / 256)   // 391 scan blocks

#define FP8_SCALE 32.0f
#define FP8_INV   0.03125f

using short8 = __attribute__((ext_vector_type(8))) short;
using f32x4  = __attribute__((ext_vector_type(4))) float;
using f32x2  = __attribute__((ext_vector_type(2))) float;

__device__ __forceinline__ float bf2f(unsigned int u) {
    union { unsigned int i; float f; } x; x.i = u << 16; return x.f;
}
__device__ __forceinline__ unsigned short f2bf(float f) {
    __hip_bfloat16 h = __float2bfloat16(f);
    return *reinterpret_cast<unsigned short*>(&h);
}
__device__ __forceinline__ unsigned int pack2(float lo, float hi) {
    return ((unsigned int)f2bf(hi) << 16) | f2bf(lo);
}
__device__ __forceinline__ unsigned char f2fp8(float v) {
    unsigned int p = __builtin_amdgcn_cvt_pk_fp8_f32(v, v, 0, false);
    return (unsigned char)(p & 0xffu);
}
__device__ __forceinline__ f32x2 fp8x2f(unsigned int u16) {
    return __builtin_amdgcn_cvt_pk_f32_fp8(u16, false);
}

// ---------------- init: rowcnt=0, sums=0, cnt=0 ----------------
__global__ void k_init(int* __restrict__ rowcnt, float* __restrict__ s1,
                       float* __restrict__ s2, float* __restrict__ cnt) {
    int i = blockIdx.x * 256 + threadIdx.x;   // grid covers 128000
    if (i < NN) rowcnt[i] = 0;
    if (i < CC * 128) { s1[i] = 0.f; s2[i] = 0.f; }
    if (i < CC) cnt[i] = 0.f;
}

// ---------------- degree histogram over dst ----------------
__global__ void k_counti(const int* __restrict__ dst, int* __restrict__ rowcnt) {
    int i = blockIdx.x * 256 + threadIdx.x;
    if (i < EE) atomicAdd(&rowcnt[dst[i]], 1);
}

// ---------------- scan step 1: per-block sums (+ dis = rsqrt(deg+1)) ----------------
__global__ void k_blocksum(const int* __restrict__ rowcnt, int* __restrict__ bsum,
                           float* __restrict__ dis) {
    __shared__ int sd[256];
    int t = threadIdx.x, i = blockIdx.x * 256 + t;
    int v = (i < NN) ? rowcnt[i] : 0;
    sd[t] = v;
    if (i < NN) dis[i] = rsqrtf((float)v + 1.0f);
    __syncthreads();
    for (int s = 128; s > 0; s >>= 1) {
        if (t < s) sd[t] += sd[t + s];
        __syncthreads();
    }
    if (t == 0) bsum[blockIdx.x] = sd[0];
}

// ---------------- scan step 2: exclusive scan of block sums (1 block) ----------------
__global__ void k_scanb(int* __restrict__ bsum) {
    __shared__ int sd[512];
    int t = threadIdx.x;
    int v = (t < NB) ? bsum[t] : 0;
    sd[t] = v;
    __syncthreads();
    for (int off = 1; off < 512; off <<= 1) {
        int x = (t >= off) ? sd[t - off] : 0;
        __syncthreads();
        sd[t] += x;
        __syncthreads();
    }
    if (t < NB) bsum[t] = sd[t] - v;   // exclusive
}

// ---------------- scan step 3: write row offsets, zero rowcnt for reuse ----------------
__global__ void k_writeofs(int* __restrict__ rowcnt, const int* __restrict__ bsum,
                           int* __restrict__ rowofs) {
    __shared__ int sd[256];
    int t = threadIdx.x, i = blockIdx.x * 256 + t;
    int v = (i < NN) ? rowcnt[i] : 0;
    sd[t] = v;
    __syncthreads();
    for (int off = 1; off < 256; off <<= 1) {
        int x = (t >= off) ? sd[t - off] : 0;
        __syncthreads();
        sd[t] += x;
        __syncthreads();
    }
    if (i < NN) {
        rowofs[i] = bsum[blockIdx.x] + sd[t] - v;
        rowcnt[i] = 0;                 // reset for fill pass
    }
    if (i == 0) rowofs[NN] = EE;
}

// ---------------- CSR fill: packed {src, norm} sorted by dst ----------------
__global__ void k_fill(const int* __restrict__ src, const int* __restrict__ dst,
                       const float* __restrict__ dis,
                       const int* __restrict__ rowofs, int* __restrict__ rowcnt,
                       int2* __restrict__ csr) {
    int e = blockIdx.x * 256 + threadIdx.x;
    if (e >= EE) return;
    int d = dst[e], s = src[e];
    int pos = rowofs[d] + atomicAdd(&rowcnt[d], 1);
    csr[pos] = make_int2(s, __float_as_int(dis[s] * dis[d]));
}

// ---------------- weight convert+transpose (all 3): W[K][N] f32 -> Wt[N][K+8] bf16 ----------------
__global__ void k_wconv(const float* __restrict__ W3, unsigned short* __restrict__ W3t,
                        const float* __restrict__ Wc1, unsigned short* __restrict__ Wc1t,
                        const float* __restrict__ Wc2, unsigned short* __restrict__ Wc2t) {
    int y = blockIdx.y;
    int k = blockIdx.x * 256 + threadIdx.x;
    if (y < 320) {              // W3: K=320, N=320
        if (k < 328) W3t[(size_t)y * 328 + k] = (k < 320) ? f2bf(W3[(size_t)k * 320 + y]) : 0;
    } else if (y < 448) {       // Wc1: K=320, N=128
        int n = y - 320;
        if (k < 328) Wc1t[(size_t)n * 328 + k] = (k < 320) ? f2bf(Wc1[(size_t)k * 128 + n]) : 0;
    } else {                    // Wc2: K=128, N=128
        int n = y - 448;
        if (k < 136) Wc2t[(size_t)n * 136 + k] = (k < 128) ? f2bf(Wc2[(size_t)k * 128 + n]) : 0;
    }
}

// ---------------- embed: h0 = [relu(x[:, :7]W1+b1) | relu(x[:,7:]W2+b2) | id], bf16 ----------------
__global__ __launch_bounds__(256) void k_embed(
    const float* __restrict__ x, const float* __restrict__ id_emb,
    const float* __restrict__ W1, const float* __restrict__ b1,
    const float* __restrict__ W2, const float* __restrict__ b2,
    unsigned short* __restrict__ h0) {
    __shared__ float W1s[7][128];
    __shared__ float W2s[12][128];
    __shared__ float b1s[128], b2s[128];
    __shared__ float xs[4][20];
    int t = threadIdx.x;
    for (int i = t; i < 7 * 128; i += 256) ((float*)W1s)[i] = W1[i];
    for (int i = t; i < 12 * 128; i += 256) ((float*)W2s)[i] = W2[i];
    if (t < 128) { b1s[t] = b1[t]; b2s[t] = b2[t]; }
    int ln = t >> 6, lane = t & 63;
    int node = blockIdx.x * 4 + ln;
    if (node < NN && lane < 19) xs[ln][lane] = x[(size_t)node * 19 + lane];
    __syncthreads();
    if (node >= NN) return;
    unsigned int* orow = (unsigned int*)(h0 + (size_t)node * 320);
    int c2 = lane * 2;
    float a0 = b1s[c2], a1 = b1s[c2 + 1];
    #pragma unroll
    for (int k = 0; k < 7; ++k) {
        float xv = xs[ln][k];
        float2 w = *(const float2*)&W1s[k][c2];
        a0 += xv * w.x; a1 += xv * w.y;
    }
    orow[lane] = pack2(fmaxf(a0, 0.f), fmaxf(a1, 0.f));
    a0 = b2s[c2]; a1 = b2s[c2 + 1];
    #pragma unroll
    for (int k = 0; k < 12; ++k) {
        float xv = xs[ln][7 + k];
        float2 w = *(const float2*)&W2s[k][c2];
        a0 += xv * w.x; a1 += xv * w.y;
    }
    orow[64 + lane] = pack2(fmaxf(a0, 0.f), fmaxf(a1, 0.f));
    if (lane < 32) {
        float2 iv = *(const float2*)(id_emb + (size_t)node * 64 + c2);
        orow[128 + lane] = pack2(iv.x, iv.y);
    }
}

// ---------------- unified bf16 MFMA GEMM, K-chunked A&B staging ----------------
// OUT8=0: C bf16 with optional bias+relu.  OUT8=1: C fp8 (scaled by FP8_SCALE).
template <int K, int N, int RELU, int OUT8>
__global__ __launch_bounds__(256) void k_bgemm(
    const unsigned short* __restrict__ A, const unsigned short* __restrict__ Bt,
    const float* __restrict__ bias, void* __restrict__ Cv, int M) {
    constexpr int NT = (N + 127) / 128;
    __shared__ __align__(16) short As[128][40];
    __shared__ __align__(16) short Bs[128][40];
    int t = threadIdx.x;
    int bid = blockIdx.x;
    int ct = bid % NT, rblk = bid / NT;
    int rowBase = rblk * 128, colBase = ct * 128;
    int wid = t >> 6, lane = t & 63;
    int wm = wid >> 1, wn = wid & 1;
    int fr = lane & 15, g = lane >> 4;
    f32x4 acc[4][4] = {};
    for (int kb = 0; kb < K; kb += 32) {
        __syncthreads();   // LDS reuse guard
        #pragma unroll
        for (int p = 0; p < 2; ++p) {
            int ci = t + 256 * p;
            int r = ci >> 2, q = ci & 3;
            int gr = rowBase + r;
            short8 v = {};
            if (gr < M) v = *(const short8*)(A + (size_t)gr * K + kb + q * 8);
            *(short8*)&As[r][q * 8] = v;
        }
        #pragma unroll
        for (int p = 0; p < 2; ++p) {
            int ci = t + 256 * p;
            int r = ci >> 2, q = ci & 3;
            int gc = colBase + r;
            short8 v = {};
            if (gc < N) v = *(const short8*)(Bt + (size_t)gc * (K + 8) + kb + q * 8);
            *(short8*)&Bs[r][q * 8] = v;
        }
        __syncthreads();
        short8 bfr[4];
        #pragma unroll
        for (int nf = 0; nf < 4; ++nf)
            bfr[nf] = *(const short8*)&Bs[wn * 64 + nf * 16 + fr][g * 8];
        #pragma unroll
        for (int mf = 0; mf < 4; ++mf) {
            short8 a = *(const short8*)&As[wm * 64 + mf * 16 + fr][g * 8];
            #pragma unroll
            for (int nf = 0; nf < 4; ++nf)
                acc[mf][nf] = __builtin_amdgcn_mfma_f32_16x16x32_bf16(a, bfr[nf], acc[mf][nf], 0, 0, 0);
        }
    }
    #pragma unroll
    for (int nf = 0; nf < 4; ++nf) {
        int col = colBase + wn * 64 + nf * 16 + fr;
        if (col < N) {
            float bv = RELU ? bias[col] : 0.f;
            #pragma unroll
            for (int mf = 0; mf < 4; ++mf) {
                #pragma unroll
                for (int r = 0; r < 4; ++r) {
                    int row = rowBase + wm * 64 + mf * 16 + g * 4 + r;
                    if (row < M) {
                        float v = acc[mf][nf][r];
                        if (OUT8) {
                            ((unsigned char*)Cv)[(size_t)row * N + col] = f2fp8(v * FP8_SCALE);
                        } else {
                            if (RELU) v = fmaxf(v + bv, 0.f);
                            ((unsigned short*)Cv)[(size_t)row * N + col] = f2bf(v);
                        }
                    }
                }
            }
        }
    }
}

// ---------------- fused gather conv (fp8 in / bf16 out):
// h = relu((sum hw8[src]*norm + hw8[wid]*dis^2)/SCALE + b) + community-pool atomics ----------------
__global__ __launch_bounds__(256) void k_gather(
    const int* __restrict__ rowofs, const int2* __restrict__ csr,
    const float* __restrict__ dis, const unsigned char* __restrict__ hw8,
    const float* __restrict__ bias, const int* __restrict__ comm,
    unsigned short* __restrict__ hout, float* __restrict__ sums,
    float* __restrict__ cnt, int doCnt) {
    int wid = blockIdx.x * 4 + (threadIdx.x >> 6);
    wid = __builtin_amdgcn_readfirstlane(wid);
    int lane = threadIdx.x & 63;
    if (wid >= NN) return;
    int ro = rowofs[wid], re = rowofs[wid + 1];
    int c = lane * 2;
    float dsd = dis[wid];
    float self = dsd * dsd;
    unsigned int hv = *(const unsigned short*)(hw8 + (size_t)wid * 128 + c);
    f32x2 hf = fp8x2f(hv);
    float a0 = hf.x * self;          // scaled space
    float a1 = hf.y * self;
    int e = ro;
    for (; e + 16 <= re; e += 16) {
        int2 pk[16]; unsigned int v[16];
        #pragma unroll
        for (int j = 0; j < 16; ++j) pk[j] = csr[e + j];
        #pragma unroll
        for (int j = 0; j < 16; ++j)
            v[j] = *(const unsigned short*)(hw8 + (size_t)pk[j].x * 128 + c);
        #pragma unroll
        for (int j = 0; j < 16; ++j) {
            float n = __int_as_float(pk[j].y);
            f32x2 f = fp8x2f(v[j]);
            a0 += f.x * n;
            a1 += f.y * n;
        }
    }
    for (; e + 4 <= re; e += 4) {
        int2 pk[4]; unsigned int v[4];
        #pragma unroll
        for (int j = 0; j < 4; ++j) pk[j] = csr[e + j];
        #pragma unroll
        for (int j = 0; j < 4; ++j)
            v[j] = *(const unsigned short*)(hw8 + (size_t)pk[j].x * 128 + c);
        #pragma unroll
        for (int j = 0; j < 4; ++j) {
            float n = __int_as_float(pk[j].y);
            f32x2 f = fp8x2f(v[j]);
            a0 += f.x * n;
            a1 += f.y * n;
        }
    }
    for (; e < re; ++e) {
        int2 pk = csr[e];
        float n = __int_as_float(pk.y);
        unsigned int v0 = *(const unsigned short*)(hw8 + (size_t)pk.x * 128 + c);
        f32x2 f = fp8x2f(v0);
        a0 += f.x * n;
        a1 += f.y * n;
    }
    a0 = fmaxf(a0 * FP8_INV + bias[c], 0.f);
    a1 = fmaxf(a1 * FP8_INV + bias[c + 1], 0.f);
    *(unsigned int*)(hout + (size_t)wid * 128 + c) = pack2(a0, a1);
    int cm = comm[wid];
    atomicAdd(sums + (size_t)cm * 128 + c + 0, a0);
    atomicAdd(sums + (size_t)cm * 128 + c + 1, a1);
    if (doCnt && lane == 0) atomicAdd(cnt + cm, 1.0f);
}

// ---------------- final MLP over communities (fp32) ----------------
__global__ __launch_bounds__(128) void k_final(
    const float* __restrict__ s1, const float* __restrict__ s2,
    const float* __restrict__ cnt,
    const float* __restrict__ Wl1, const float* __restrict__ bl1,
    const float* __restrict__ Wl2, const float* __restrict__ bl2,
    float* __restrict__ out) {
    __shared__ float zh[128];
    __shared__ float partial[2];
    int c = blockIdx.x, t = threadIdx.x;
    float invc = 1.0f / fmaxf(cnt[c], 1.0f);
    zh[t] = (s1[(size_t)c * 128 + t] + s2[(size_t)c * 128 + t]) * invc;
    __syncthreads();
    float acc = bl1[t];
    for (int k = 0; k < 128; ++k)
        acc += zh[k] * (Wl1[(size_t)k * 128 + t] + Wl1[(size_t)(k + 128) * 128 + t]);
    float zv = fmaxf(acc, 0.f);
    float p = zv * Wl2[t];
    #pragma unroll
    for (int off = 32; off > 0; off >>= 1) p += __shfl_down(p, off, 64);
    if ((t & 63) == 0) partial[t >> 6] = p;
    __syncthreads();
    if (t == 0) out[c] = partial[0] + partial[1] + bl2[0];
}

extern "C" void kernel_launch(void* const* d_in, const int* in_sizes, int n_in,
                              void* d_out, int out_size, void* d_ws, size_t ws_size,
                              hipStream_t stream) {
    const float* x       = (const float*)d_in[0];
    const int*   edge    = (const int*)d_in[1];
    const int*   comm    = (const int*)d_in[2];
    const float* id_emb  = (const float*)d_in[3];
    const float* W1      = (const float*)d_in[4];
    const float* b1      = (const float*)d_in[5];
    const float* W2      = (const float*)d_in[6];
    const float* b2      = (const float*)d_in[7];
    const float* W3      = (const float*)d_in[8];
    const float* b3      = (const float*)d_in[9];
    const float* Wc1     = (const float*)d_in[10];
    const float* bc1     = (const float*)d_in[11];
    const float* Wc2     = (const float*)d_in[12];
    const float* bc2     = (const float*)d_in[13];
    const float* Wl1     = (const float*)d_in[14];
    const float* bl1     = (const float*)d_in[15];
    const float* Wl2     = (const float*)d_in[16];
    const float* bl2     = (const float*)d_in[17];
    float* out = (float*)d_out;
    float* ws  = (float*)d_ws;

    const int* srcIdx = edge;
    const int* dstIdx = edge + EE;

    size_t o = 0;
    auto alloc = [&](size_t nfloats) {
        float* p = ws + o; o += (nfloats + 3) & ~(size_t)3; return p;
    };
    float* dis   = alloc(NN);
    float* cnt   = alloc(1024);
    float* s1    = alloc((size_t)CC * 128);
    float* s2    = alloc((size_t)CC * 128);
    int* rowcnt  = (int*)alloc(NN);
    int* rowofs  = (int*)alloc(NN + 8);
    int* bsum    = (int*)alloc(512);
    int2* csr    = (int2*)alloc((size_t)EE * 2);
    unsigned short* W3t  = (unsigned short*)alloc(320 * 328 / 2);
    unsigned short* Wc1t = (unsigned short*)alloc(128 * 328 / 2);
    unsigned short* Wc2t = (unsigned short*)alloc(128 * 136 / 2);
    unsigned short* h0   = (unsigned short*)alloc((size_t)NN * 320 / 2);
    unsigned short* h1   = (unsigned short*)alloc((size_t)NN * 320 / 2);
    unsigned char*  hw8  = (unsigned char*)alloc((size_t)NN * 128 / 4);
    unsigned short* h23  = (unsigned short*)alloc((size_t)NN * 128 / 2);

    // ---- CSR build + degree norm ----
    k_init<<<500, 256, 0, stream>>>(rowcnt, s1, s2, cnt);
    k_counti<<<EE / 256, 256, 0, stream>>>(dstIdx, rowcnt);
    k_blocksum<<<NB, 256, 0, stream>>>(rowcnt, bsum, dis);
    k_scanb<<<1, 512, 0, stream>>>(bsum);
    k_writeofs<<<NB, 256, 0, stream>>>(rowcnt, bsum, rowofs);
    k_fill<<<EE / 256, 256, 0, stream>>>(srcIdx, dstIdx, dis, rowofs, rowcnt, csr);

    // ---- weight convert/transpose to bf16 (one launch) ----
    k_wconv<<<dim3(2, 576), 256, 0, stream>>>(W3, W3t, Wc1, Wc1t, Wc2, Wc2t);

    // ---- embedding (bf16 out) ----
    k_embed<<<(NN + 3) / 4, 256, 0, stream>>>(x, id_emb, W1, b1, W2, b2, h0);

    int rb = (NN + 127) / 128;   // 782
    // h1 = relu(h0 @ W3 + b3)   (3 col-tiles, ct fastest for A locality)
    k_bgemm<320, 320, 1, 0><<<rb * 3, 256, 0, stream>>>(h0, W3t, b3, h1, NN);
    // ---- conv1: hw8 = fp8(h1 @ Wc1 * SCALE) ----
    k_bgemm<320, 128, 0, 1><<<rb, 256, 0, stream>>>(h1, Wc1t, nullptr, hw8, NN);
    k_gather<<<(NN + 3) / 4, 256, 0, stream>>>(rowofs, csr, dis, hw8,
                                               bc1, comm, h23, s1, cnt, 1);
    // ---- conv2: hw8 = fp8(h2 @ Wc2 * SCALE) ----
    k_bgemm<128, 128, 0, 1><<<rb, 256, 0, stream>>>(h23, Wc2t, nullptr, hw8, NN);
    k_gather<<<(NN + 3) / 4, 256, 0, stream>>>(rowofs, csr, dis, hw8,
                                               bc2, comm, h23, s2, cnt, 0);

    // ---- final MLP ----
    k_final<<<CC, 128, 0, stream>>>(s1, s2, cnt, Wl1, bl1, Wl2, bl2, out);
}

// Round 8
// 541.138 us; speedup vs baseline: 1.3598x; 1.1032x over previous
//
#include <hip/hip_runtime.h>
#include <hip/hip_bf16.h>
#include <cstddef>

#define NN 100000
#define EE 1600000
#define CC 1000
#define NB ((NN + 255) / 256)   // 391 scan blocks

#define FP8_SCALE 32.0f
#define FP8_INV   0.03125f

using short8 = __attribute__((ext_vector_type(8))) short;
using f32x4  = __attribute__((ext_vector_type(4))) float;
using f32x2  = __attribute__((ext_vector_type(2))) float;

__device__ __forceinline__ float bf2f(unsigned int u) {
    union { unsigned int i; float f; } x; x.i = u << 16; return x.f;
}
__device__ __forceinline__ unsigned short f2bf(float f) {
    __hip_bfloat16 h = __float2bfloat16(f);
    return *reinterpret_cast<unsigned short*>(&h);
}
__device__ __forceinline__ unsigned int pack2(float lo, float hi) {
    return ((unsigned int)f2bf(hi) << 16) | f2bf(lo);
}
__device__ __forceinline__ unsigned char f2fp8(float v) {
    unsigned int p = __builtin_amdgcn_cvt_pk_fp8_f32(v, v, 0, false);
    return (unsigned char)(p & 0xffu);
}
__device__ __forceinline__ f32x2 fp8x2f(unsigned int u16) {
    return __builtin_amdgcn_cvt_pk_f32_fp8(u16, false);
}

// ---------------- init: rowcnt=0, commcnt=0 ----------------
__global__ void k_init(int* __restrict__ rowcnt, int* __restrict__ commcnt) {
    int i = blockIdx.x * 256 + threadIdx.x;   // grid covers 128000
    if (i < NN) rowcnt[i] = 0;
    if (i < CC) commcnt[i] = 0;
}

// ---------------- degree histogram over dst ----------------
__global__ void k_counti(const int* __restrict__ dst, int* __restrict__ rowcnt) {
    int i = blockIdx.x * 256 + threadIdx.x;
    if (i < EE) atomicAdd(&rowcnt[dst[i]], 1);
}

// ---------------- scan step 1: block sums + dis + community histogram ----------------
__global__ void k_blocksum(const int* __restrict__ rowcnt, int* __restrict__ bsum,
                           float* __restrict__ dis, const int* __restrict__ comm,
                           int* __restrict__ commcnt) {
    __shared__ int sd[256];
    int t = threadIdx.x, i = blockIdx.x * 256 + t;
    int v = (i < NN) ? rowcnt[i] : 0;
    sd[t] = v;
    if (i < NN) {
        dis[i] = rsqrtf((float)v + 1.0f);
        atomicAdd(&commcnt[comm[i]], 1);
    }
    __syncthreads();
    for (int s = 128; s > 0; s >>= 1) {
        if (t < s) sd[t] += sd[t + s];
        __syncthreads();
    }
    if (t == 0) bsum[blockIdx.x] = sd[0];
}

// ---------------- scan step 2: exclusive scan of block sums (1 block) ----------------
__global__ void k_scanb(int* __restrict__ bsum) {
    __shared__ int sd[512];
    int t = threadIdx.x;
    int v = (t < NB) ? bsum[t] : 0;
    sd[t] = v;
    __syncthreads();
    for (int off = 1; off < 512; off <<= 1) {
        int x = (t >= off) ? sd[t - off] : 0;
        __syncthreads();
        sd[t] += x;
        __syncthreads();
    }
    if (t < NB) bsum[t] = sd[t] - v;   // exclusive
}

// ---------------- scan step 3: write row offsets, zero rowcnt for reuse ----------------
__global__ void k_writeofs(int* __restrict__ rowcnt, const int* __restrict__ bsum,
                           int* __restrict__ rowofs) {
    __shared__ int sd[256];
    int t = threadIdx.x, i = blockIdx.x * 256 + t;
    int v = (i < NN) ? rowcnt[i] : 0;
    sd[t] = v;
    __syncthreads();
    for (int off = 1; off < 256; off <<= 1) {
        int x = (t >= off) ? sd[t - off] : 0;
        __syncthreads();
        sd[t] += x;
        __syncthreads();
    }
    if (i < NN) {
        rowofs[i] = bsum[blockIdx.x] + sd[t] - v;
        rowcnt[i] = 0;                 // reset for fill pass
    }
    if (i == 0) rowofs[NN] = EE;
}

// ---------------- CSR fill: packed {src, norm} sorted by dst ----------------
__global__ void k_fill(const int* __restrict__ src, const int* __restrict__ dst,
                       const float* __restrict__ dis,
                       const int* __restrict__ rowofs, int* __restrict__ rowcnt,
                       int2* __restrict__ csr) {
    int e = blockIdx.x * 256 + threadIdx.x;
    if (e >= EE) return;
    int d = dst[e], s = src[e];
    int pos = rowofs[d] + atomicAdd(&rowcnt[d], 1);
    csr[pos] = make_int2(s, __float_as_int(dis[s] * dis[d]));
}

// ---------------- community scan (1 block over CC=1000) + zero commcnt ----------------
__global__ void k_scanc(int* __restrict__ commcnt, int* __restrict__ commofs) {
    __shared__ int sd[1024];
    int t = threadIdx.x;
    int v = (t < CC) ? commcnt[t] : 0;
    sd[t] = v;
    __syncthreads();
    for (int off = 1; off < 1024; off <<= 1) {
        int x = (t >= off) ? sd[t - off] : 0;
        __syncthreads();
        sd[t] += x;
        __syncthreads();
    }
    if (t < CC) {
        commofs[t] = sd[t] - v;        // exclusive
        commcnt[t] = 0;                // reset for fill pass
    }
    if (t == CC - 1) commofs[CC] = sd[t];
}

// ---------------- community member fill ----------------
__global__ void k_fillc(const int* __restrict__ comm, const int* __restrict__ commofs,
                        int* __restrict__ commcnt, int* __restrict__ members) {
    int i = blockIdx.x * 256 + threadIdx.x;
    if (i >= NN) return;
    int c = comm[i];
    int pos = commofs[c] + atomicAdd(&commcnt[c], 1);
    members[pos] = i;
}

// ---------------- weight convert+transpose (all 3): W[K][N] f32 -> Wt[N][K+8] bf16 ----------------
__global__ void k_wconv(const float* __restrict__ W3, unsigned short* __restrict__ W3t,
                        const float* __restrict__ Wc1, unsigned short* __restrict__ Wc1t,
                        const float* __restrict__ Wc2, unsigned short* __restrict__ Wc2t) {
    int y = blockIdx.y;
    int k = blockIdx.x * 256 + threadIdx.x;
    if (y < 320) {              // W3: K=320, N=320
        if (k < 328) W3t[(size_t)y * 328 + k] = (k < 320) ? f2bf(W3[(size_t)k * 320 + y]) : 0;
    } else if (y < 448) {       // Wc1: K=320, N=128
        int n = y - 320;
        if (k < 328) Wc1t[(size_t)n * 328 + k] = (k < 320) ? f2bf(Wc1[(size_t)k * 128 + n]) : 0;
    } else {                    // Wc2: K=128, N=128
        int n = y - 448;
        if (k < 136) Wc2t[(size_t)n * 136 + k] = (k < 128) ? f2bf(Wc2[(size_t)k * 128 + n]) : 0;
    }
}

// ---------------- embed: h0 = [relu(x[:, :7]W1+b1) | relu(x[:,7:]W2+b2) | id], bf16 ----------------
__global__ __launch_bounds__(256) void k_embed(
    const float* __restrict__ x, const float* __restrict__ id_emb,
    const float* __restrict__ W1, const float* __restrict__ b1,
    const float* __restrict__ W2, const float* __restrict__ b2,
    unsigned short* __restrict__ h0) {
    __shared__ float W1s[7][128];
    __shared__ float W2s[12][128];
    __shared__ float b1s[128], b2s[128];
    __shared__ float xs[4][20];
    int t = threadIdx.x;
    for (int i = t; i < 7 * 128; i += 256) ((float*)W1s)[i] = W1[i];
    for (int i = t; i < 12 * 128; i += 256) ((float*)W2s)[i] = W2[i];
    if (t < 128) { b1s[t] = b1[t]; b2s[t] = b2[t]; }
    int ln = t >> 6, lane = t & 63;
    int node = blockIdx.x * 4 + ln;
    if (node < NN && lane < 19) xs[ln][lane] = x[(size_t)node * 19 + lane];
    __syncthreads();
    if (node >= NN) return;
    unsigned int* orow = (unsigned int*)(h0 + (size_t)node * 320);
    int c2 = lane * 2;
    float a0 = b1s[c2], a1 = b1s[c2 + 1];
    #pragma unroll
    for (int k = 0; k < 7; ++k) {
        float xv = xs[ln][k];
        float2 w = *(const float2*)&W1s[k][c2];
        a0 += xv * w.x; a1 += xv * w.y;
    }
    orow[lane] = pack2(fmaxf(a0, 0.f), fmaxf(a1, 0.f));
    a0 = b2s[c2]; a1 = b2s[c2 + 1];
    #pragma unroll
    for (int k = 0; k < 12; ++k) {
        float xv = xs[ln][7 + k];
        float2 w = *(const float2*)&W2s[k][c2];
        a0 += xv * w.x; a1 += xv * w.y;
    }
    orow[64 + lane] = pack2(fmaxf(a0, 0.f), fmaxf(a1, 0.f));
    if (lane < 32) {
        float2 iv = *(const float2*)(id_emb + (size_t)node * 64 + c2);
        orow[128 + lane] = pack2(iv.x, iv.y);
    }
}

// ---------------- unified bf16 MFMA GEMM, K-chunked A&B staging ----------------
// OUT8=0: C bf16 with optional bias+relu.  OUT8=1: C fp8 (scaled by FP8_SCALE).
template <int K, int N, int RELU, int OUT8>
__global__ __launch_bounds__(256) void k_bgemm(
    const unsigned short* __restrict__ A, const unsigned short* __restrict__ Bt,
    const float* __restrict__ bias, void* __restrict__ Cv, int M) {
    constexpr int NT = (N + 127) / 128;
    __shared__ __align__(16) short As[128][40];
    __shared__ __align__(16) short Bs[128][40];
    int t = threadIdx.x;
    int bid = blockIdx.x;
    int ct = bid % NT, rblk = bid / NT;
    int rowBase = rblk * 128, colBase = ct * 128;
    int wid = t >> 6, lane = t & 63;
    int wm = wid >> 1, wn = wid & 1;
    int fr = lane & 15, g = lane >> 4;
    f32x4 acc[4][4] = {};
    for (int kb = 0; kb < K; kb += 32) {
        __syncthreads();   // LDS reuse guard
        #pragma unroll
        for (int p = 0; p < 2; ++p) {
            int ci = t + 256 * p;
            int r = ci >> 2, q = ci & 3;
            int gr = rowBase + r;
            short8 v = {};
            if (gr < M) v = *(const short8*)(A + (size_t)gr * K + kb + q * 8);
            *(short8*)&As[r][q * 8] = v;
        }
        #pragma unroll
        for (int p = 0; p < 2; ++p) {
            int ci = t + 256 * p;
            int r = ci >> 2, q = ci & 3;
            int gc = colBase + r;
            short8 v = {};
            if (gc < N) v = *(const short8*)(Bt + (size_t)gc * (K + 8) + kb + q * 8);
            *(short8*)&Bs[r][q * 8] = v;
        }
        __syncthreads();
        short8 bfr[4];
        #pragma unroll
        for (int nf = 0; nf < 4; ++nf)
            bfr[nf] = *(const short8*)&Bs[wn * 64 + nf * 16 + fr][g * 8];
        #pragma unroll
        for (int mf = 0; mf < 4; ++mf) {
            short8 a = *(const short8*)&As[wm * 64 + mf * 16 + fr][g * 8];
            #pragma unroll
            for (int nf = 0; nf < 4; ++nf)
                acc[mf][nf] = __builtin_amdgcn_mfma_f32_16x16x32_bf16(a, bfr[nf], acc[mf][nf], 0, 0, 0);
        }
    }
    #pragma unroll
    for (int nf = 0; nf < 4; ++nf) {
        int col = colBase + wn * 64 + nf * 16 + fr;
        if (col < N) {
            float bv = RELU ? bias[col] : 0.f;
            #pragma unroll
            for (int mf = 0; mf < 4; ++mf) {
                #pragma unroll
                for (int r = 0; r < 4; ++r) {
                    int row = rowBase + wm * 64 + mf * 16 + g * 4 + r;
                    if (row < M) {
                        float v = acc[mf][nf][r];
                        if (OUT8) {
                            ((unsigned char*)Cv)[(size_t)row * N + col] = f2fp8(v * FP8_SCALE);
                        } else {
                            if (RELU) v = fmaxf(v + bv, 0.f);
                            ((unsigned short*)Cv)[(size_t)row * N + col] = f2bf(v);
                        }
                    }
                }
            }
        }
    }
}

// ---------------- pure gather conv (fp8 in / bf16 out):
// h = relu((sum hw8[src]*norm + hw8[wid]*dis^2)/SCALE + b) ----------------
__global__ __launch_bounds__(256) void k_gather(
    const int* __restrict__ rowofs, const int2* __restrict__ csr,
    const float* __restrict__ dis, const unsigned char* __restrict__ hw8,
    const float* __restrict__ bias, unsigned short* __restrict__ hout) {
    int wid = blockIdx.x * 4 + (threadIdx.x >> 6);
    wid = __builtin_amdgcn_readfirstlane(wid);
    int lane = threadIdx.x & 63;
    if (wid >= NN) return;
    int ro = rowofs[wid], re = rowofs[wid + 1];
    int c = lane * 2;
    float dsd = dis[wid];
    float self = dsd * dsd;
    unsigned int hv = *(const unsigned short*)(hw8 + (size_t)wid * 128 + c);
    f32x2 hf = fp8x2f(hv);
    float a0 = hf.x * self;          // scaled space
    float a1 = hf.y * self;
    int e = ro;
    for (; e + 16 <= re; e += 16) {
        int2 pk[16]; unsigned int v[16];
        #pragma unroll
        for (int j = 0; j < 16; ++j) pk[j] = csr[e + j];
        #pragma unroll
        for (int j = 0; j < 16; ++j)
            v[j] = *(const unsigned short*)(hw8 + (size_t)pk[j].x * 128 + c);
        #pragma unroll
        for (int j = 0; j < 16; ++j) {
            float n = __int_as_float(pk[j].y);
            f32x2 f = fp8x2f(v[j]);
            a0 += f.x * n;
            a1 += f.y * n;
        }
    }
    for (; e + 4 <= re; e += 4) {
        int2 pk[4]; unsigned int v[4];
        #pragma unroll
        for (int j = 0; j < 4; ++j) pk[j] = csr[e + j];
        #pragma unroll
        for (int j = 0; j < 4; ++j)
            v[j] = *(const unsigned short*)(hw8 + (size_t)pk[j].x * 128 + c);
        #pragma unroll
        for (int j = 0; j < 4; ++j) {
            float n = __int_as_float(pk[j].y);
            f32x2 f = fp8x2f(v[j]);
            a0 += f.x * n;
            a1 += f.y * n;
        }
    }
    for (; e < re; ++e) {
        int2 pk = csr[e];
        float n = __int_as_float(pk.y);
        unsigned int v0 = *(const unsigned short*)(hw8 + (size_t)pk.x * 128 + c);
        f32x2 f = fp8x2f(v0);
        a0 += f.x * n;
        a1 += f.y * n;
    }
    a0 = fmaxf(a0 * FP8_INV + bias[c], 0.f);
    a1 = fmaxf(a1 * FP8_INV + bias[c + 1], 0.f);
    *(unsigned int*)(hout + (size_t)wid * 128 + c) = pack2(a0, a1);
}

// ---------------- final: community pool (CSR, no atomics) + MLP ----------------
__global__ __launch_bounds__(128) void k_final(
    const unsigned short* __restrict__ h2, const unsigned short* __restrict__ h3,
    const int* __restrict__ commofs, const int* __restrict__ members,
    const float* __restrict__ Wl1, const float* __restrict__ bl1,
    const float* __restrict__ Wl2, const float* __restrict__ bl2,
    float* __restrict__ out) {
    __shared__ float zh[128];
    __shared__ float partial[2];
    int c = blockIdx.x, t = threadIdx.x;
    int ro = commofs[c], re = commofs[c + 1];
    float acc = 0.f;
    int e = ro;
    for (; e + 4 <= re; e += 4) {
        int m0 = members[e], m1 = members[e + 1];
        int m2 = members[e + 2], m3 = members[e + 3];
        acc += bf2f(h2[(size_t)m0 * 128 + t]) + bf2f(h3[(size_t)m0 * 128 + t]);
        acc += bf2f(h2[(size_t)m1 * 128 + t]) + bf2f(h3[(size_t)m1 * 128 + t]);
        acc += bf2f(h2[(size_t)m2 * 128 + t]) + bf2f(h3[(size_t)m2 * 128 + t]);
        acc += bf2f(h2[(size_t)m3 * 128 + t]) + bf2f(h3[(size_t)m3 * 128 + t]);
    }
    for (; e < re; ++e) {
        int m = members[e];
        acc += bf2f(h2[(size_t)m * 128 + t]) + bf2f(h3[(size_t)m * 128 + t]);
    }
    float invc = 1.0f / fmaxf((float)(re - ro), 1.0f);
    zh[t] = acc * invc;
    __syncthreads();
    float a = bl1[t];
    for (int k = 0; k < 128; ++k)
        a += zh[k] * (Wl1[(size_t)k * 128 + t] + Wl1[(size_t)(k + 128) * 128 + t]);
    float zv = fmaxf(a, 0.f);
    float p = zv * Wl2[t];
    #pragma unroll
    for (int off = 32; off > 0; off >>= 1) p += __shfl_down(p, off, 64);
    if ((t & 63) == 0) partial[t >> 6] = p;
    __syncthreads();
    if (t == 0) out[c] = partial[0] + partial[1] + bl2[0];
}

extern "C" void kernel_launch(void* const* d_in, const int* in_sizes, int n_in,
                              void* d_out, int out_size, void* d_ws, size_t ws_size,
                              hipStream_t stream) {
    const float* x       = (const float*)d_in[0];
    const int*   edge    = (const int*)d_in[1];
    const int*   comm    = (const int*)d_in[2];
    const float* id_emb  = (const float*)d_in[3];
    const float* W1      = (const float*)d_in[4];
    const float* b1      = (const float*)d_in[5];
    const float* W2      = (const float*)d_in[6];
    const float* b2      = (const float*)d_in[7];
    const float* W3      = (const float*)d_in[8];
    const float* b3      = (const float*)d_in[9];
    const float* Wc1     = (const float*)d_in[10];
    const float* bc1     = (const float*)d_in[11];
    const float* Wc2     = (const float*)d_in[12];
    const float* bc2     = (const float*)d_in[13];
    const float* Wl1     = (const float*)d_in[14];
    const float* bl1     = (const float*)d_in[15];
    const float* Wl2     = (const float*)d_in[16];
    const float* bl2     = (const float*)d_in[17];
    float* out = (float*)d_out;
    float* ws  = (float*)d_ws;

    const int* srcIdx = edge;
    const int* dstIdx = edge + EE;

    size_t o = 0;
    auto alloc = [&](size_t nfloats) {
        float* p = ws + o; o += (nfloats + 3) & ~(size_t)3; return p;
    };
    float* dis    = alloc(NN);
    int* rowcnt   = (int*)alloc(NN);
    int* rowofs   = (int*)alloc(NN + 8);
    int* bsum     = (int*)alloc(512);
    int* commcnt  = (int*)alloc(1024);
    int* commofs  = (int*)alloc(1024 + 8);
    int* members  = (int*)alloc(NN);
    int2* csr     = (int2*)alloc((size_t)EE * 2);
    unsigned short* W3t  = (unsigned short*)alloc(320 * 328 / 2);
    unsigned short* Wc1t = (unsigned short*)alloc(128 * 328 / 2);
    unsigned short* Wc2t = (unsigned short*)alloc(128 * 136 / 2);
    unsigned short* h0   = (unsigned short*)alloc((size_t)NN * 320 / 2);
    unsigned short* h1   = (unsigned short*)alloc((size_t)NN * 320 / 2);
    unsigned char*  hw8  = (unsigned char*)alloc((size_t)NN * 128 / 4);
    unsigned short* h2   = (unsigned short*)alloc((size_t)NN * 128 / 2);
    unsigned short* h3   = (unsigned short*)alloc((size_t)NN * 128 / 2);

    // ---- CSR build + degree norm + community CSR ----
    k_init<<<500, 256, 0, stream>>>(rowcnt, commcnt);
    k_counti<<<EE / 256, 256, 0, stream>>>(dstIdx, rowcnt);
    k_blocksum<<<NB, 256, 0, stream>>>(rowcnt, bsum, dis, comm, commcnt);
    k_scanb<<<1, 512, 0, stream>>>(bsum);
    k_writeofs<<<NB, 256, 0, stream>>>(rowcnt, bsum, rowofs);
    k_fill<<<EE / 256, 256, 0, stream>>>(srcIdx, dstIdx, dis, rowofs, rowcnt, csr);
    k_scanc<<<1, 1024, 0, stream>>>(commcnt, commofs);
    k_fillc<<<NB, 256, 0, stream>>>(comm, commofs, commcnt, members);

    // ---- weight convert/transpose to bf16 (one launch) ----
    k_wconv<<<dim3(2, 576), 256, 0, stream>>>(W3, W3t, Wc1, Wc1t, Wc2, Wc2t);

    // ---- embedding (bf16 out) ----
    k_embed<<<(NN + 3) / 4, 256, 0, stream>>>(x, id_emb, W1, b1, W2, b2, h0);

    int rb = (NN + 127) / 128;   // 782
    // h1 = relu(h0 @ W3 + b3)   (3 col-tiles, ct fastest for A locality)
    k_bgemm<320, 320, 1, 0><<<rb * 3, 256, 0, stream>>>(h0, W3t, b3, h1, NN);
    // ---- conv1: hw8 = fp8(h1 @ Wc1 * SCALE) ----
    k_bgemm<320, 128, 0, 1><<<rb, 256, 0, stream>>>(h1, Wc1t, nullptr, hw8, NN);
    k_gather<<<(NN + 3) / 4, 256, 0, stream>>>(rowofs, csr, dis, hw8, bc1, h2);
    // ---- conv2: hw8 = fp8(h2 @ Wc2 * SCALE) ----
    k_bgemm<128, 128, 0, 1><<<rb, 256, 0, stream>>>(h2, Wc2t, nullptr, hw8, NN);
    k_gather<<<(NN + 3) / 4, 256, 0, stream>>>(rowofs, csr, dis, hw8, bc2, h3);

    // ---- final: pool + MLP ----
    k_final<<<CC, 128, 0, stream>>>(h2, h3, commofs, members, Wl1, bl1, Wl2, bl2, out);
}

// Round 9
// 479.134 us; speedup vs baseline: 1.5358x; 1.1294x over previous
//
#include <hip/hip_runtime.h>
#include <hip/hip_bf16.h>
#include <cstddef>

#define NN 100000
#define EE 1600000
#define CC 1000
#define NB ((NN + 255) / 256)   // 391 scan blocks

#define FP8_SCALE 32.0f
#define FP8_INV   0.03125f

using short8 = __attribute__((ext_vector_type(8))) short;
using f32x4  = __attribute__((ext_vector_type(4))) float;
using f32x2  = __attribute__((ext_vector_type(2))) float;

__device__ __forceinline__ float bf2f(unsigned int u) {
    union { unsigned int i; float f; } x; x.i = u << 16; return x.f;
}
__device__ __forceinline__ unsigned short f2bf(float f) {
    __hip_bfloat16 h = __float2bfloat16(f);
    return *reinterpret_cast<unsigned short*>(&h);
}
__device__ __forceinline__ unsigned int pack2(float lo, float hi) {
    return ((unsigned int)f2bf(hi) << 16) | f2bf(lo);
}
__device__ __forceinline__ unsigned char f2fp8(float v) {
    unsigned int p = __builtin_amdgcn_cvt_pk_fp8_f32(v, v, 0, false);
    return (unsigned char)(p & 0xffu);
}
__device__ __forceinline__ f32x2 fp8x2f(unsigned int u16) {
    return __builtin_amdgcn_cvt_pk_f32_fp8(u16, false);
}

// ---------------- init: rowcnt=0, commcnt=0 ----------------
__global__ void k_init(int* __restrict__ rowcnt, int* __restrict__ commcnt) {
    int i = blockIdx.x * 256 + threadIdx.x;
    if (i < NN) rowcnt[i] = 0;
    if (i < CC) commcnt[i] = 0;
}

// ---------------- degree histogram over dst ----------------
__global__ void k_counti(const int* __restrict__ dst, int* __restrict__ rowcnt) {
    int i = blockIdx.x * 256 + threadIdx.x;
    if (i < EE) atomicAdd(&rowcnt[dst[i]], 1);
}

// ---------------- scan step 1: block sums + dis + community histogram ----------------
__global__ void k_blocksum(const int* __restrict__ rowcnt, int* __restrict__ bsum,
                           float* __restrict__ dis, const int* __restrict__ comm,
                           int* __restrict__ commcnt) {
    __shared__ int sd[256];
    int t = threadIdx.x, i = blockIdx.x * 256 + t;
    int v = (i < NN) ? rowcnt[i] : 0;
    sd[t] = v;
    if (i < NN) {
        dis[i] = rsqrtf((float)v + 1.0f);
        atomicAdd(&commcnt[comm[i]], 1);
    }
    __syncthreads();
    for (int s = 128; s > 0; s >>= 1) {
        if (t < s) sd[t] += sd[t + s];
        __syncthreads();
    }
    if (t == 0) bsum[blockIdx.x] = sd[0];
}

// ---------------- scan step 2: exclusive scan of block sums (1 block) ----------------
__global__ void k_scanb(int* __restrict__ bsum) {
    __shared__ int sd[512];
    int t = threadIdx.x;
    int v = (t < NB) ? bsum[t] : 0;
    sd[t] = v;
    __syncthreads();
    for (int off = 1; off < 512; off <<= 1) {
        int x = (t >= off) ? sd[t - off] : 0;
        __syncthreads();
        sd[t] += x;
        __syncthreads();
    }
    if (t < NB) bsum[t] = sd[t] - v;   // exclusive
}

// ---------------- scan step 3: write row offsets, zero rowcnt for reuse ----------------
__global__ void k_writeofs(int* __restrict__ rowcnt, const int* __restrict__ bsum,
                           int* __restrict__ rowofs) {
    __shared__ int sd[256];
    int t = threadIdx.x, i = blockIdx.x * 256 + t;
    int v = (i < NN) ? rowcnt[i] : 0;
    sd[t] = v;
    __syncthreads();
    for (int off = 1; off < 256; off <<= 1) {
        int x = (t >= off) ? sd[t - off] : 0;
        __syncthreads();
        sd[t] += x;
        __syncthreads();
    }
    if (i < NN) {
        rowofs[i] = bsum[blockIdx.x] + sd[t] - v;
        rowcnt[i] = 0;                 // reset for fill pass
    }
    if (i == 0) rowofs[NN] = EE;
}

// ---------------- CSR fill: packed {src, norm} sorted by dst ----------------
__global__ void k_fill(const int* __restrict__ src, const int* __restrict__ dst,
                       const float* __restrict__ dis,
                       const int* __restrict__ rowofs, int* __restrict__ rowcnt,
                       int2* __restrict__ csr) {
    int e = blockIdx.x * 256 + threadIdx.x;
    if (e >= EE) return;
    int d = dst[e], s = src[e];
    int pos = rowofs[d] + atomicAdd(&rowcnt[d], 1);
    csr[pos] = make_int2(s, __float_as_int(dis[s] * dis[d]));
}

// ---------------- community scan (1 block over CC=1000) + zero commcnt ----------------
__global__ void k_scanc(int* __restrict__ commcnt, int* __restrict__ commofs) {
    __shared__ int sd[1024];
    int t = threadIdx.x;
    int v = (t < CC) ? commcnt[t] : 0;
    sd[t] = v;
    __syncthreads();
    for (int off = 1; off < 1024; off <<= 1) {
        int x = (t >= off) ? sd[t - off] : 0;
        __syncthreads();
        sd[t] += x;
        __syncthreads();
    }
    if (t < CC) {
        commofs[t] = sd[t] - v;        // exclusive
        commcnt[t] = 0;                // reset for fill pass
    }
    if (t == CC - 1) commofs[CC] = sd[t];
}

// ---------------- community member fill ----------------
__global__ void k_fillc(const int* __restrict__ comm, const int* __restrict__ commofs,
                        int* __restrict__ commcnt, int* __restrict__ members) {
    int i = blockIdx.x * 256 + threadIdx.x;
    if (i >= NN) return;
    int c = comm[i];
    int pos = commofs[c] + atomicAdd(&commcnt[c], 1);
    members[pos] = i;
}

// ---------------- weight convert+transpose (all 3): W[K][N] f32 -> Wt[N][K+8] bf16 ----------------
__global__ void k_wconv(const float* __restrict__ W3, unsigned short* __restrict__ W3t,
                        const float* __restrict__ Wc1, unsigned short* __restrict__ Wc1t,
                        const float* __restrict__ Wc2, unsigned short* __restrict__ Wc2t) {
    int y = blockIdx.y;
    int k = blockIdx.x * 256 + threadIdx.x;
    if (y < 320) {              // W3: K=320, N=320
        if (k < 328) W3t[(size_t)y * 328 + k] = (k < 320) ? f2bf(W3[(size_t)k * 320 + y]) : 0;
    } else if (y < 448) {       // Wc1: K=320, N=128
        int n = y - 320;
        if (k < 328) Wc1t[(size_t)n * 328 + k] = (k < 320) ? f2bf(Wc1[(size_t)k * 128 + n]) : 0;
    } else {                    // Wc2: K=128, N=128
        int n = y - 448;
        if (k < 136) Wc2t[(size_t)n * 136 + k] = (k < 128) ? f2bf(Wc2[(size_t)k * 128 + n]) : 0;
    }
}

// ---------------- embed: h0 = [relu(x[:, :7]W1+b1) | relu(x[:,7:]W2+b2) | id], bf16 ----------------
__global__ __launch_bounds__(256) void k_embed(
    const float* __restrict__ x, const float* __restrict__ id_emb,
    const float* __restrict__ W1, const float* __restrict__ b1,
    const float* __restrict__ W2, const float* __restrict__ b2,
    unsigned short* __restrict__ h0) {
    __shared__ float W1s[7][128];
    __shared__ float W2s[12][128];
    __shared__ float b1s[128], b2s[128];
    __shared__ float xs[4][20];
    int t = threadIdx.x;
    for (int i = t; i < 7 * 128; i += 256) ((float*)W1s)[i] = W1[i];
    for (int i = t; i < 12 * 128; i += 256) ((float*)W2s)[i] = W2[i];
    if (t < 128) { b1s[t] = b1[t]; b2s[t] = b2[t]; }
    int ln = t >> 6, lane = t & 63;
    int node = blockIdx.x * 4 + ln;
    if (node < NN && lane < 19) xs[ln][lane] = x[(size_t)node * 19 + lane];
    __syncthreads();
    if (node >= NN) return;
    unsigned int* orow = (unsigned int*)(h0 + (size_t)node * 320);
    int c2 = lane * 2;
    float a0 = b1s[c2], a1 = b1s[c2 + 1];
    #pragma unroll
    for (int k = 0; k < 7; ++k) {
        float xv = xs[ln][k];
        float2 w = *(const float2*)&W1s[k][c2];
        a0 += xv * w.x; a1 += xv * w.y;
    }
    orow[lane] = pack2(fmaxf(a0, 0.f), fmaxf(a1, 0.f));
    a0 = b2s[c2]; a1 = b2s[c2 + 1];
    #pragma unroll
    for (int k = 0; k < 12; ++k) {
        float xv = xs[ln][7 + k];
        float2 w = *(const float2*)&W2s[k][c2];
        a0 += xv * w.x; a1 += xv * w.y;
    }
    orow[64 + lane] = pack2(fmaxf(a0, 0.f), fmaxf(a1, 0.f));
    if (lane < 32) {
        float2 iv = *(const float2*)(id_emb + (size_t)node * 64 + c2);
        orow[128 + lane] = pack2(iv.x, iv.y);
    }
}

// ---------------- unified bf16 MFMA GEMM, reg-prefetch pipeline + coalesced epilogue ----------------
// OUT8=0: C bf16 [+bias+relu].  OUT8=1 (N must be 128): C fp8 scaled by FP8_SCALE.
template <int K, int N, int RELU, int OUT8>
__global__ __launch_bounds__(256) void k_bgemm(
    const unsigned short* __restrict__ A, const unsigned short* __restrict__ Bt,
    const float* __restrict__ bias, void* __restrict__ Cv, int M) {
    constexpr int NT = (N + 127) / 128;
    __shared__ __align__(16) short sbuf[2 * 128 * 40];   // 20480 B: As | Bs, reused by epilogue
    short (*As)[40] = (short(*)[40])sbuf;
    short (*Bs)[40] = (short(*)[40])(sbuf + 128 * 40);
    int t = threadIdx.x;
    int bid = blockIdx.x;
    int ct = bid % NT, rblk = bid / NT;
    int rowBase = rblk * 128, colBase = ct * 128;
    int wid = t >> 6, lane = t & 63;
    int wm = wid >> 1, wn = wid & 1;
    int fr = lane & 15, g = lane >> 4;
    int rr = t >> 2;              // 0..63 staging row
    int qq = (t & 3) * 8;         // k-subchunk
    f32x4 acc[4][4] = {};
    short8 z = {};
    short8 pA0, pA1, pB0, pB1;
    int grA0 = rowBase + rr, grA1 = grA0 + 64;
    int gcB0 = colBase + rr, gcB1 = gcB0 + 64;
    // prefetch k=0
    pA0 = (grA0 < M) ? *(const short8*)(A + (size_t)grA0 * K + qq) : z;
    pA1 = (grA1 < M) ? *(const short8*)(A + (size_t)grA1 * K + qq) : z;
    pB0 = (gcB0 < N) ? *(const short8*)(Bt + (size_t)gcB0 * (K + 8) + qq) : z;
    pB1 = (gcB1 < N) ? *(const short8*)(Bt + (size_t)gcB1 * (K + 8) + qq) : z;
    for (int kb = 0; kb < K; kb += 32) {
        __syncthreads();                    // LDS consumers of prev step done
        *(short8*)&As[rr][qq]      = pA0;
        *(short8*)&As[rr + 64][qq] = pA1;
        *(short8*)&Bs[rr][qq]      = pB0;
        *(short8*)&Bs[rr + 64][qq] = pB1;
        __syncthreads();                    // LDS ready
        if (kb + 32 < K) {                  // issue next-step loads under MFMA
            int kn = kb + 32;
            pA0 = (grA0 < M) ? *(const short8*)(A + (size_t)grA0 * K + kn + qq) : z;
            pA1 = (grA1 < M) ? *(const short8*)(A + (size_t)grA1 * K + kn + qq) : z;
            pB0 = (gcB0 < N) ? *(const short8*)(Bt + (size_t)gcB0 * (K + 8) + kn + qq) : z;
            pB1 = (gcB1 < N) ? *(const short8*)(Bt + (size_t)gcB1 * (K + 8) + kn + qq) : z;
        }
        short8 bfr[4];
        #pragma unroll
        for (int nf = 0; nf < 4; ++nf)
            bfr[nf] = *(const short8*)&Bs[wn * 64 + nf * 16 + fr][g * 8];
        #pragma unroll
        for (int mf = 0; mf < 4; ++mf) {
            short8 a = *(const short8*)&As[wm * 64 + mf * 16 + fr][g * 8];
            #pragma unroll
            for (int nf = 0; nf < 4; ++nf)
                acc[mf][nf] = __builtin_amdgcn_mfma_f32_16x16x32_bf16(a, bfr[nf], acc[mf][nf], 0, 0, 0);
        }
    }
    // ---- epilogue: LDS transpose -> coalesced 16B stores ----
    if (!OUT8) {
        unsigned short* sb = (unsigned short*)sbuf;
        #pragma unroll
        for (int cc = 0; cc < 2; ++cc) {
            int cbase = colBase + cc * 64;
            if (cbase < N) {                       // uniform per block
                __syncthreads();
                if (wn == cc) {
                    #pragma unroll
                    for (int nf = 0; nf < 4; ++nf) {
                        int colL = nf * 16 + fr;
                        float bv = RELU ? bias[cbase + colL] : 0.f;
                        #pragma unroll
                        for (int mf = 0; mf < 4; ++mf) {
                            #pragma unroll
                            for (int r = 0; r < 4; ++r) {
                                int row = wm * 64 + mf * 16 + g * 4 + r;
                                float v = acc[mf][nf][r];
                                if (RELU) v = fmaxf(v + bv, 0.f);
                                sb[row * 64 + colL] = f2bf(v);
                            }
                        }
                    }
                }
                __syncthreads();
                #pragma unroll
                for (int i = 0; i < 4; ++i) {
                    int off8 = t + 256 * i;        // 16-B chunk id (1024 total)
                    int row = off8 >> 3;
                    int col = (off8 & 7) * 8;
                    int grow = rowBase + row;
                    if (grow < M)
                        *(short8*)((unsigned short*)Cv + (size_t)grow * N + cbase + col) =
                            *(const short8*)&sb[row * 64 + col];
                }
            }
        }
    } else {
        unsigned char* sb8 = (unsigned char*)sbuf;  // 128x128 fp8 tile = 16 KB
        __syncthreads();
        #pragma unroll
        for (int nf = 0; nf < 4; ++nf) {
            int colL = wn * 64 + nf * 16 + fr;
            #pragma unroll
            for (int mf = 0; mf < 4; ++mf) {
                #pragma unroll
                for (int r = 0; r < 4; ++r) {
                    int row = wm * 64 + mf * 16 + g * 4 + r;
                    sb8[row * 128 + colL] = f2fp8(acc[mf][nf][r] * FP8_SCALE);
                }
            }
        }
        __syncthreads();
        #pragma unroll
        for (int i = 0; i < 4; ++i) {
            int off16 = t + 256 * i;               // 16-B chunk id (1024 total)
            int row = off16 >> 3;
            int col = (off16 & 7) * 16;
            int grow = rowBase + row;
            if (grow < M)
                *(int4*)((unsigned char*)Cv + (size_t)grow * N + col) =
                    *(const int4*)&sb8[row * 128 + col];
        }
    }
}

// ---------------- pure gather conv (fp8 in / bf16 out):
// h = relu((sum hw8[src]*norm + hw8[wid]*dis^2)/SCALE + b) ----------------
__global__ __launch_bounds__(256) void k_gather(
    const int* __restrict__ rowofs, const int2* __restrict__ csr,
    const float* __restrict__ dis, const unsigned char* __restrict__ hw8,
    const float* __restrict__ bias, unsigned short* __restrict__ hout) {
    int wid = blockIdx.x * 4 + (threadIdx.x >> 6);
    wid = __builtin_amdgcn_readfirstlane(wid);
    int lane = threadIdx.x & 63;
    if (wid >= NN) return;
    int ro = rowofs[wid], re = rowofs[wid + 1];
    int c = lane * 2;
    float dsd = dis[wid];
    float self = dsd * dsd;
    unsigned int hv = *(const unsigned short*)(hw8 + (size_t)wid * 128 + c);
    f32x2 hf = fp8x2f(hv);
    float a0 = hf.x * self;          // scaled space
    float a1 = hf.y * self;
    int e = ro;
    for (; e + 16 <= re; e += 16) {
        int2 pk[16]; unsigned int v[16];
        #pragma unroll
        for (int j = 0; j < 16; ++j) pk[j] = csr[e + j];
        #pragma unroll
        for (int j = 0; j < 16; ++j)
            v[j] = *(const unsigned short*)(hw8 + (size_t)pk[j].x * 128 + c);
        #pragma unroll
        for (int j = 0; j < 16; ++j) {
            float n = __int_as_float(pk[j].y);
            f32x2 f = fp8x2f(v[j]);
            a0 += f.x * n;
            a1 += f.y * n;
        }
    }
    for (; e + 4 <= re; e += 4) {
        int2 pk[4]; unsigned int v[4];
        #pragma unroll
        for (int j = 0; j < 4; ++j) pk[j] = csr[e + j];
        #pragma unroll
        for (int j = 0; j < 4; ++j)
            v[j] = *(const unsigned short*)(hw8 + (size_t)pk[j].x * 128 + c);
        #pragma unroll
        for (int j = 0; j < 4; ++j) {
            float n = __int_as_float(pk[j].y);
            f32x2 f = fp8x2f(v[j]);
            a0 += f.x * n;
            a1 += f.y * n;
        }
    }
    for (; e < re; ++e) {
        int2 pk = csr[e];
        float n = __int_as_float(pk.y);
        unsigned int v0 = *(const unsigned short*)(hw8 + (size_t)pk.x * 128 + c);
        f32x2 f = fp8x2f(v0);
        a0 += f.x * n;
        a1 += f.y * n;
    }
    a0 = fmaxf(a0 * FP8_INV + bias[c], 0.f);
    a1 = fmaxf(a1 * FP8_INV + bias[c + 1], 0.f);
    *(unsigned int*)(hout + (size_t)wid * 128 + c) = pack2(a0, a1);
}

// ---------------- final: community pool (CSR, no atomics) + MLP ----------------
__global__ __launch_bounds__(128) void k_final(
    const unsigned short* __restrict__ h2, const unsigned short* __restrict__ h3,
    const int* __restrict__ commofs, const int* __restrict__ members,
    const float* __restrict__ Wl1, const float* __restrict__ bl1,
    const float* __restrict__ Wl2, const float* __restrict__ bl2,
    float* __restrict__ out) {
    __shared__ float zh[128];
    __shared__ float partial[2];
    int c = blockIdx.x, t = threadIdx.x;
    int ro = commofs[c], re = commofs[c + 1];
    float acc = 0.f;
    int e = ro;
    for (; e + 4 <= re; e += 4) {
        int m0 = members[e], m1 = members[e + 1];
        int m2 = members[e + 2], m3 = members[e + 3];
        acc += bf2f(h2[(size_t)m0 * 128 + t]) + bf2f(h3[(size_t)m0 * 128 + t]);
        acc += bf2f(h2[(size_t)m1 * 128 + t]) + bf2f(h3[(size_t)m1 * 128 + t]);
        acc += bf2f(h2[(size_t)m2 * 128 + t]) + bf2f(h3[(size_t)m2 * 128 + t]);
        acc += bf2f(h2[(size_t)m3 * 128 + t]) + bf2f(h3[(size_t)m3 * 128 + t]);
    }
    for (; e < re; ++e) {
        int m = members[e];
        acc += bf2f(h2[(size_t)m * 128 + t]) + bf2f(h3[(size_t)m * 128 + t]);
    }
    float invc = 1.0f / fmaxf((float)(re - ro), 1.0f);
    zh[t] = acc * invc;
    __syncthreads();
    float a = bl1[t];
    for (int k = 0; k < 128; ++k)
        a += zh[k] * (Wl1[(size_t)k * 128 + t] + Wl1[(size_t)(k + 128) * 128 + t]);
    float zv = fmaxf(a, 0.f);
    float p = zv * Wl2[t];
    #pragma unroll
    for (int off = 32; off > 0; off >>= 1) p += __shfl_down(p, off, 64);
    if ((t & 63) == 0) partial[t >> 6] = p;
    __syncthreads();
    if (t == 0) out[c] = partial[0] + partial[1] + bl2[0];
}

extern "C" void kernel_launch(void* const* d_in, const int* in_sizes, int n_in,
                              void* d_out, int out_size, void* d_ws, size_t ws_size,
                              hipStream_t stream) {
    const float* x       = (const float*)d_in[0];
    const int*   edge    = (const int*)d_in[1];
    const int*   comm    = (const int*)d_in[2];
    const float* id_emb  = (const float*)d_in[3];
    const float* W1      = (const float*)d_in[4];
    const float* b1      = (const float*)d_in[5];
    const float* W2      = (const float*)d_in[6];
    const float* b2      = (const float*)d_in[7];
    const float* W3      = (const float*)d_in[8];
    const float* b3      = (const float*)d_in[9];
    const float* Wc1     = (const float*)d_in[10];
    const float* bc1     = (const float*)d_in[11];
    const float* Wc2     = (const float*)d_in[12];
    const float* bc2     = (const float*)d_in[13];
    const float* Wl1     = (const float*)d_in[14];
    const float* bl1     = (const float*)d_in[15];
    const float* Wl2     = (const float*)d_in[16];
    const float* bl2     = (const float*)d_in[17];
    float* out = (float*)d_out;
    float* ws  = (float*)d_ws;

    const int* srcIdx = edge;
    const int* dstIdx = edge + EE;

    size_t o = 0;
    auto alloc = [&](size_t nfloats) {
        float* p = ws + o; o += (nfloats + 3) & ~(size_t)3; return p;
    };
    float* dis    = alloc(NN);
    int* rowcnt   = (int*)alloc(NN);
    int* rowofs   = (int*)alloc(NN + 8);
    int* bsum     = (int*)alloc(512);
    int* commcnt  = (int*)alloc(1024);
    int* commofs  = (int*)alloc(1024 + 8);
    int* members  = (int*)alloc(NN);
    int2* csr     = (int2*)alloc((size_t)EE * 2);
    unsigned short* W3t  = (unsigned short*)alloc(320 * 328 / 2);
    unsigned short* Wc1t = (unsigned short*)alloc(128 * 328 / 2);
    unsigned short* Wc2t = (unsigned short*)alloc(128 * 136 / 2);
    unsigned short* h0   = (unsigned short*)alloc((size_t)NN * 320 / 2);
    unsigned short* h1   = (unsigned short*)alloc((size_t)NN * 320 / 2);
    unsigned char*  hw8  = (unsigned char*)alloc((size_t)NN * 128 / 4);
    unsigned short* h2   = (unsigned short*)alloc((size_t)NN * 128 / 2);
    unsigned short* h3   = (unsigned short*)alloc((size_t)NN * 128 / 2);

    // ---- CSR build + degree norm + community CSR ----
    k_init<<<500, 256, 0, stream>>>(rowcnt, commcnt);
    k_counti<<<EE / 256, 256, 0, stream>>>(dstIdx, rowcnt);
    k_blocksum<<<NB, 256, 0, stream>>>(rowcnt, bsum, dis, comm, commcnt);
    k_scanb<<<1, 512, 0, stream>>>(bsum);
    k_writeofs<<<NB, 256, 0, stream>>>(rowcnt, bsum, rowofs);
    k_fill<<<EE / 256, 256, 0, stream>>>(srcIdx, dstIdx, dis, rowofs, rowcnt, csr);
    k_scanc<<<1, 1024, 0, stream>>>(commcnt, commofs);
    k_fillc<<<NB, 256, 0, stream>>>(comm, commofs, commcnt, members);

    // ---- weight convert/transpose to bf16 (one launch) ----
    k_wconv<<<dim3(2, 576), 256, 0, stream>>>(W3, W3t, Wc1, Wc1t, Wc2, Wc2t);

    // ---- embedding (bf16 out) ----
    k_embed<<<(NN + 3) / 4, 256, 0, stream>>>(x, id_emb, W1, b1, W2, b2, h0);

    int rb = (NN + 127) / 128;   // 782
    // h1 = relu(h0 @ W3 + b3)   (3 col-tiles, ct fastest for A locality)
    k_bgemm<320, 320, 1, 0><<<rb * 3, 256, 0, stream>>>(h0, W3t, b3, h1, NN);
    // ---- conv1: hw8 = fp8(h1 @ Wc1 * SCALE) ----
    k_bgemm<320, 128, 0, 1><<<rb, 256, 0, stream>>>(h1, Wc1t, nullptr, hw8, NN);
    k_gather<<<(NN + 3) / 4, 256, 0, stream>>>(rowofs, csr, dis, hw8, bc1, h2);
    // ---- conv2: hw8 = fp8(h2 @ Wc2 * SCALE) ----
    k_bgemm<128, 128, 0, 1><<<rb, 256, 0, stream>>>(h2, Wc2t, nullptr, hw8, NN);
    k_gather<<<(NN + 3) / 4, 256, 0, stream>>>(rowofs, csr, dis, hw8, bc2, h3);

    // ---- final: pool + MLP ----
    k_final<<<CC, 128, 0, stream>>>(h2, h3, commofs, members, Wl1, bl1, Wl2, bl2, out);
}

// Round 10
// 419.665 us; speedup vs baseline: 1.7535x; 1.1417x over previous
//
#include <hip/hip_runtime.h>
#include <hip/hip_bf16.h>
#include <cstddef>

#define NN 100000
#define EE 1600000
#define CC 1000
#define NBK ((NN + 255) / 256)   // 391 dst buckets of 256 nodes
#define EPB 4096                  // edges per block in bucketize pass

#define FP8_SCALE 32.0f
#define FP8_INV   0.03125f

using short8 = __attribute__((ext_vector_type(8))) short;
using f32x4  = __attribute__((ext_vector_type(4))) float;
using f32x2  = __attribute__((ext_vector_type(2))) float;

__device__ __forceinline__ float bf2f(unsigned int u) {
    union { unsigned int i; float f; } x; x.i = u << 16; return x.f;
}
__device__ __forceinline__ unsigned short f2bf(float f) {
    __hip_bfloat16 h = __float2bfloat16(f);
    return *reinterpret_cast<unsigned short*>(&h);
}
__device__ __forceinline__ unsigned int pack2(float lo, float hi) {
    return ((unsigned int)f2bf(hi) << 16) | f2bf(lo);
}
__device__ __forceinline__ unsigned char f2fp8(float v) {
    unsigned int p = __builtin_amdgcn_cvt_pk_fp8_f32(v, v, 0, false);
    return (unsigned char)(p & 0xffu);
}
__device__ __forceinline__ f32x2 fp8x2f(unsigned int u16) {
    return __builtin_amdgcn_cvt_pk_f32_fp8(u16, false);
}

// ---------------- init: bucketCnt=0, bucketFill=0, commcnt=0 ----------------
__global__ void k_init(int* __restrict__ bucketCnt, int* __restrict__ bucketFill,
                       int* __restrict__ commcnt) {
    int i = blockIdx.x * 256 + threadIdx.x;   // grid covers 1024
    if (i < NBK) { bucketCnt[i] = 0; bucketFill[i] = 0; }
    if (i < CC) commcnt[i] = 0;
}

// ---------------- pass A0: bucket histogram (LDS-staged) ----------------
__global__ __launch_bounds__(256) void k_bhist(const int* __restrict__ dst,
                                               int* __restrict__ bucketCnt) {
    __shared__ int hist[NBK];
    int t = threadIdx.x;
    for (int i = t; i < NBK; i += 256) hist[i] = 0;
    __syncthreads();
    int base = blockIdx.x * EPB;
    for (int i = t; i < EPB; i += 256) {
        int e = base + i;
        if (e < EE) atomicAdd(&hist[dst[e] >> 8], 1);
    }
    __syncthreads();
    for (int i = t; i < NBK; i += 256)
        if (hist[i]) atomicAdd(&bucketCnt[i], hist[i]);
}

// ---------------- pass A-scan: exclusive scan of bucket counts (1 block) ----------------
__global__ void k_bscan(const int* __restrict__ bucketCnt, int* __restrict__ bucketBase) {
    __shared__ int sd[512];
    int t = threadIdx.x;
    int v = (t < NBK) ? bucketCnt[t] : 0;
    sd[t] = v;
    __syncthreads();
    for (int off = 1; off < 512; off <<= 1) {
        int x = (t >= off) ? sd[t - off] : 0;
        __syncthreads();
        sd[t] += x;
        __syncthreads();
    }
    if (t < NBK) bucketBase[t] = sd[t] - v;   // exclusive
    if (t == 0) bucketBase[NBK] = EE;
}

// ---------------- pass A1: partition edges into bucket regions ----------------
__global__ __launch_bounds__(256) void k_bucketize(
    const int* __restrict__ src, const int* __restrict__ dst,
    const int* __restrict__ bucketBase, int* __restrict__ bucketFill,
    int2* __restrict__ bkt) {
    __shared__ int hist[NBK];
    __shared__ int runPos[NBK];
    int t = threadIdx.x;
    for (int i = t; i < NBK; i += 256) hist[i] = 0;
    __syncthreads();
    int base = blockIdx.x * EPB;
    for (int i = t; i < EPB; i += 256) {
        int e = base + i;
        if (e < EE) atomicAdd(&hist[dst[e] >> 8], 1);
    }
    __syncthreads();
    for (int i = t; i < NBK; i += 256)
        runPos[i] = hist[i] ? (bucketBase[i] + atomicAdd(&bucketFill[i], hist[i])) : 0;
    __syncthreads();
    for (int i = t; i < EPB; i += 256) {
        int e = base + i;
        if (e < EE) {
            int d = dst[e];
            int pos = atomicAdd(&runPos[d >> 8], 1);
            bkt[pos] = make_int2(src[e], d);
        }
    }
}

// ---------------- pass B: per-bucket CSR finalize (rowofs, dis, commcnt, csr src) ----------------
__global__ __launch_bounds__(256) void k_csr(
    const int2* __restrict__ bkt, const int* __restrict__ bucketBase,
    const int* __restrict__ comm, int* __restrict__ commcnt,
    int* __restrict__ rowofs, float* __restrict__ dis, int* __restrict__ csr) {
    __shared__ int cnt[256], sd[256], cnt2[256];
    int b = blockIdx.x, t = threadIdx.x;
    int base = bucketBase[b], end = bucketBase[b + 1];
    int nodeBase = b << 8;
    cnt[t] = 0; cnt2[t] = 0;
    __syncthreads();
    for (int i = base + t; i < end; i += 256)
        atomicAdd(&cnt[bkt[i].y - nodeBase], 1);
    __syncthreads();
    int v = cnt[t];
    sd[t] = v;
    __syncthreads();
    for (int off = 1; off < 256; off <<= 1) {
        int x = (t >= off) ? sd[t - off] : 0;
        __syncthreads();
        sd[t] += x;
        __syncthreads();
    }
    int ofs = sd[t] - v;           // exclusive local offset
    sd[t] = ofs;
    int node = nodeBase + t;
    if (node < NN) {
        rowofs[node] = base + ofs;
        dis[node] = rsqrtf((float)v + 1.0f);
        atomicAdd(&commcnt[comm[node]], 1);
    }
    if (b == NBK - 1 && t == 0) rowofs[NN] = EE;
    __syncthreads();
    for (int i = base + t; i < end; i += 256) {
        int2 ed = bkt[i];
        int ld = ed.y - nodeBase;
        int p = atomicAdd(&cnt2[ld], 1);
        csr[base + sd[ld] + p] = ed.x;
    }
}

// ---------------- community scan (1 block over CC=1000) + zero commcnt ----------------
__global__ void k_scanc(int* __restrict__ commcnt, int* __restrict__ commofs) {
    __shared__ int sd[1024];
    int t = threadIdx.x;
    int v = (t < CC) ? commcnt[t] : 0;
    sd[t] = v;
    __syncthreads();
    for (int off = 1; off < 1024; off <<= 1) {
        int x = (t >= off) ? sd[t - off] : 0;
        __syncthreads();
        sd[t] += x;
        __syncthreads();
    }
    if (t < CC) {
        commofs[t] = sd[t] - v;        // exclusive
        commcnt[t] = 0;                // reset for fill pass
    }
    if (t == CC - 1) commofs[CC] = sd[t];
}

// ---------------- community member fill ----------------
__global__ void k_fillc(const int* __restrict__ comm, const int* __restrict__ commofs,
                        int* __restrict__ commcnt, int* __restrict__ members) {
    int i = blockIdx.x * 256 + threadIdx.x;
    if (i >= NN) return;
    int c = comm[i];
    int pos = commofs[c] + atomicAdd(&commcnt[c], 1);
    members[pos] = i;
}

// ---------------- weight convert+transpose (all 3): W[K][N] f32 -> Wt[N][K+8] bf16 ----------------
__global__ void k_wconv(const float* __restrict__ W3, unsigned short* __restrict__ W3t,
                        const float* __restrict__ Wc1, unsigned short* __restrict__ Wc1t,
                        const float* __restrict__ Wc2, unsigned short* __restrict__ Wc2t) {
    int y = blockIdx.y;
    int k = blockIdx.x * 256 + threadIdx.x;
    if (y < 320) {              // W3: K=320, N=320
        if (k < 328) W3t[(size_t)y * 328 + k] = (k < 320) ? f2bf(W3[(size_t)k * 320 + y]) : 0;
    } else if (y < 448) {       // Wc1: K=320, N=128
        int n = y - 320;
        if (k < 328) Wc1t[(size_t)n * 328 + k] = (k < 320) ? f2bf(Wc1[(size_t)k * 128 + n]) : 0;
    } else {                    // Wc2: K=128, N=128
        int n = y - 448;
        if (k < 136) Wc2t[(size_t)n * 136 + k] = (k < 128) ? f2bf(Wc2[(size_t)k * 128 + n]) : 0;
    }
}

// ---------------- embed: h0 = [relu(x[:, :7]W1+b1) | relu(x[:,7:]W2+b2) | id], bf16 ----------------
__global__ __launch_bounds__(256) void k_embed(
    const float* __restrict__ x, const float* __restrict__ id_emb,
    const float* __restrict__ W1, const float* __restrict__ b1,
    const float* __restrict__ W2, const float* __restrict__ b2,
    unsigned short* __restrict__ h0) {
    __shared__ float W1s[7][128];
    __shared__ float W2s[12][128];
    __shared__ float b1s[128], b2s[128];
    __shared__ float xs[4][20];
    int t = threadIdx.x;
    for (int i = t; i < 7 * 128; i += 256) ((float*)W1s)[i] = W1[i];
    for (int i = t; i < 12 * 128; i += 256) ((float*)W2s)[i] = W2[i];
    if (t < 128) { b1s[t] = b1[t]; b2s[t] = b2[t]; }
    int ln = t >> 6, lane = t & 63;
    int node = blockIdx.x * 4 + ln;
    if (node < NN && lane < 19) xs[ln][lane] = x[(size_t)node * 19 + lane];
    __syncthreads();
    if (node >= NN) return;
    unsigned int* orow = (unsigned int*)(h0 + (size_t)node * 320);
    int c2 = lane * 2;
    float a0 = b1s[c2], a1 = b1s[c2 + 1];
    #pragma unroll
    for (int k = 0; k < 7; ++k) {
        float xv = xs[ln][k];
        float2 w = *(const float2*)&W1s[k][c2];
        a0 += xv * w.x; a1 += xv * w.y;
    }
    orow[lane] = pack2(fmaxf(a0, 0.f), fmaxf(a1, 0.f));
    a0 = b2s[c2]; a1 = b2s[c2 + 1];
    #pragma unroll
    for (int k = 0; k < 12; ++k) {
        float xv = xs[ln][7 + k];
        float2 w = *(const float2*)&W2s[k][c2];
        a0 += xv * w.x; a1 += xv * w.y;
    }
    orow[64 + lane] = pack2(fmaxf(a0, 0.f), fmaxf(a1, 0.f));
    if (lane < 32) {
        float2 iv = *(const float2*)(id_emb + (size_t)node * 64 + c2);
        orow[128 + lane] = pack2(iv.x, iv.y);
    }
}

// ---------------- unified bf16 MFMA GEMM, reg-prefetch pipeline + coalesced epilogue ----------------
// OUT8=0: C bf16 [+bias+relu].  OUT8=1 (N must be 128): C fp8 scaled by FP8_SCALE.
template <int K, int N, int RELU, int OUT8>
__global__ __launch_bounds__(256) void k_bgemm(
    const unsigned short* __restrict__ A, const unsigned short* __restrict__ Bt,
    const float* __restrict__ bias, void* __restrict__ Cv, int M) {
    constexpr int NT = (N + 127) / 128;
    __shared__ __align__(16) short sbuf[2 * 128 * 40];   // 20480 B: As | Bs, reused by epilogue
    short (*As)[40] = (short(*)[40])sbuf;
    short (*Bs)[40] = (short(*)[40])(sbuf + 128 * 40);
    int t = threadIdx.x;
    int bid = blockIdx.x;
    int ct = bid % NT, rblk = bid / NT;
    int rowBase = rblk * 128, colBase = ct * 128;
    int wid = t >> 6, lane = t & 63;
    int wm = wid >> 1, wn = wid & 1;
    int fr = lane & 15, g = lane >> 4;
    int rr = t >> 2;              // 0..63 staging row
    int qq = (t & 3) * 8;         // k-subchunk
    f32x4 acc[4][4] = {};
    short8 z = {};
    short8 pA0, pA1, pB0, pB1;
    int grA0 = rowBase + rr, grA1 = grA0 + 64;
    int gcB0 = colBase + rr, gcB1 = gcB0 + 64;
    // prefetch k=0
    pA0 = (grA0 < M) ? *(const short8*)(A + (size_t)grA0 * K + qq) : z;
    pA1 = (grA1 < M) ? *(const short8*)(A + (size_t)grA1 * K + qq) : z;
    pB0 = (gcB0 < N) ? *(const short8*)(Bt + (size_t)gcB0 * (K + 8) + qq) : z;
    pB1 = (gcB1 < N) ? *(const short8*)(Bt + (size_t)gcB1 * (K + 8) + qq) : z;
    for (int kb = 0; kb < K; kb += 32) {
        __syncthreads();                    // LDS consumers of prev step done
        *(short8*)&As[rr][qq]      = pA0;
        *(short8*)&As[rr + 64][qq] = pA1;
        *(short8*)&Bs[rr][qq]      = pB0;
        *(short8*)&Bs[rr + 64][qq] = pB1;
        __syncthreads();                    // LDS ready
        if (kb + 32 < K) {                  // issue next-step loads under MFMA
            int kn = kb + 32;
            pA0 = (grA0 < M) ? *(const short8*)(A + (size_t)grA0 * K + kn + qq) : z;
            pA1 = (grA1 < M) ? *(const short8*)(A + (size_t)grA1 * K + kn + qq) : z;
            pB0 = (gcB0 < N) ? *(const short8*)(Bt + (size_t)gcB0 * (K + 8) + kn + qq) : z;
            pB1 = (gcB1 < N) ? *(const short8*)(Bt + (size_t)gcB1 * (K + 8) + kn + qq) : z;
        }
        short8 bfr[4];
        #pragma unroll
        for (int nf = 0; nf < 4; ++nf)
            bfr[nf] = *(const short8*)&Bs[wn * 64 + nf * 16 + fr][g * 8];
        #pragma unroll
        for (int mf = 0; mf < 4; ++mf) {
            short8 a = *(const short8*)&As[wm * 64 + mf * 16 + fr][g * 8];
            #pragma unroll
            for (int nf = 0; nf < 4; ++nf)
                acc[mf][nf] = __builtin_amdgcn_mfma_f32_16x16x32_bf16(a, bfr[nf], acc[mf][nf], 0, 0, 0);
        }
    }
    // ---- epilogue: LDS transpose -> coalesced 16B stores ----
    if (!OUT8) {
        unsigned short* sb = (unsigned short*)sbuf;
        #pragma unroll
        for (int cc = 0; cc < 2; ++cc) {
            int cbase = colBase + cc * 64;
            if (cbase < N) {                       // uniform per block
                __syncthreads();
                if (wn == cc) {
                    #pragma unroll
                    for (int nf = 0; nf < 4; ++nf) {
                        int colL = nf * 16 + fr;
                        float bv = RELU ? bias[cbase + colL] : 0.f;
                        #pragma unroll
                        for (int mf = 0; mf < 4; ++mf) {
                            #pragma unroll
                            for (int r = 0; r < 4; ++r) {
                                int row = wm * 64 + mf * 16 + g * 4 + r;
                                float v = acc[mf][nf][r];
                                if (RELU) v = fmaxf(v + bv, 0.f);
                                sb[row * 64 + colL] = f2bf(v);
                            }
                        }
                    }
                }
                __syncthreads();
                #pragma unroll
                for (int i = 0; i < 4; ++i) {
                    int off8 = t + 256 * i;        // 16-B chunk id (1024 total)
                    int row = off8 >> 3;
                    int col = (off8 & 7) * 8;
                    int grow = rowBase + row;
                    if (grow < M)
                        *(short8*)((unsigned short*)Cv + (size_t)grow * N + cbase + col) =
                            *(const short8*)&sb[row * 64 + col];
                }
            }
        }
    } else {
        unsigned char* sb8 = (unsigned char*)sbuf;  // 128x128 fp8 tile = 16 KB
        __syncthreads();
        #pragma unroll
        for (int nf = 0; nf < 4; ++nf) {
            int colL = wn * 64 + nf * 16 + fr;
            #pragma unroll
            for (int mf = 0; mf < 4; ++mf) {
                #pragma unroll
                for (int r = 0; r < 4; ++r) {
                    int row = wm * 64 + mf * 16 + g * 4 + r;
                    sb8[row * 128 + colL] = f2fp8(acc[mf][nf][r] * FP8_SCALE);
                }
            }
        }
        __syncthreads();
        #pragma unroll
        for (int i = 0; i < 4; ++i) {
            int off16 = t + 256 * i;               // 16-B chunk id (1024 total)
            int row = off16 >> 3;
            int col = (off16 & 7) * 16;
            int grow = rowBase + row;
            if (grow < M)
                *(int4*)((unsigned char*)Cv + (size_t)grow * N + col) =
                    *(const int4*)&sb8[row * 128 + col];
        }
    }
}

// ---------------- pure gather conv (fp8 in / bf16 out):
// h = relu(dis[d]*(sum hw8[src]*dis[src] + hw8[d]*dis[d])/SCALE + b) ----------------
__global__ __launch_bounds__(256) void k_gather(
    const int* __restrict__ rowofs, const int* __restrict__ csr,
    const float* __restrict__ dis, const unsigned char* __restrict__ hw8,
    const float* __restrict__ bias, unsigned short* __restrict__ hout) {
    int wid = blockIdx.x * 4 + (threadIdx.x >> 6);
    wid = __builtin_amdgcn_readfirstlane(wid);
    int lane = threadIdx.x & 63;
    if (wid >= NN) return;
    int ro = rowofs[wid], re = rowofs[wid + 1];
    int c = lane * 2;
    float dsd = dis[wid];
    unsigned int hv = *(const unsigned short*)(hw8 + (size_t)wid * 128 + c);
    f32x2 hf = fp8x2f(hv);
    float a0 = hf.x * dsd;           // scaled space; final multiply by dsd
    float a1 = hf.y * dsd;
    int e = ro;
    for (; e + 16 <= re; e += 16) {
        int s[16]; float n[16]; unsigned int v[16];
        #pragma unroll
        for (int j = 0; j < 16; ++j) s[j] = csr[e + j];
        #pragma unroll
        for (int j = 0; j < 16; ++j) n[j] = dis[s[j]];
        #pragma unroll
        for (int j = 0; j < 16; ++j)
            v[j] = *(const unsigned short*)(hw8 + (size_t)s[j] * 128 + c);
        #pragma unroll
        for (int j = 0; j < 16; ++j) {
            f32x2 f = fp8x2f(v[j]);
            a0 += f.x * n[j];
            a1 += f.y * n[j];
        }
    }
    for (; e + 4 <= re; e += 4) {
        int s[4]; float n[4]; unsigned int v[4];
        #pragma unroll
        for (int j = 0; j < 4; ++j) s[j] = csr[e + j];
        #pragma unroll
        for (int j = 0; j < 4; ++j) n[j] = dis[s[j]];
        #pragma unroll
        for (int j = 0; j < 4; ++j)
            v[j] = *(const unsigned short*)(hw8 + (size_t)s[j] * 128 + c);
        #pragma unroll
        for (int j = 0; j < 4; ++j) {
            f32x2 f = fp8x2f(v[j]);
            a0 += f.x * n[j];
            a1 += f.y * n[j];
        }
    }
    for (; e < re; ++e) {
        int s0 = csr[e];
        float n0 = dis[s0];
        unsigned int v0 = *(const unsigned short*)(hw8 + (size_t)s0 * 128 + c);
        f32x2 f = fp8x2f(v0);
        a0 += f.x * n0;
        a1 += f.y * n0;
    }
    a0 = fmaxf(a0 * dsd * FP8_INV + bias[c], 0.f);
    a1 = fmaxf(a1 * dsd * FP8_INV + bias[c + 1], 0.f);
    *(unsigned int*)(hout + (size_t)wid * 128 + c) = pack2(a0, a1);
}

// ---------------- final: community pool (CSR, no atomics) + MLP ----------------
__global__ __launch_bounds__(128) void k_final(
    const unsigned short* __restrict__ h2, const unsigned short* __restrict__ h3,
    const int* __restrict__ commofs, const int* __restrict__ members,
    const float* __restrict__ Wl1, const float* __restrict__ bl1,
    const float* __restrict__ Wl2, const float* __restrict__ bl2,
    float* __restrict__ out) {
    __shared__ float zh[128];
    __shared__ float partial[2];
    int c = blockIdx.x, t = threadIdx.x;
    int ro = commofs[c], re = commofs[c + 1];
    float acc = 0.f;
    int e = ro;
    for (; e + 4 <= re; e += 4) {
        int m0 = members[e], m1 = members[e + 1];
        int m2 = members[e + 2], m3 = members[e + 3];
        acc += bf2f(h2[(size_t)m0 * 128 + t]) + bf2f(h3[(size_t)m0 * 128 + t]);
        acc += bf2f(h2[(size_t)m1 * 128 + t]) + bf2f(h3[(size_t)m1 * 128 + t]);
        acc += bf2f(h2[(size_t)m2 * 128 + t]) + bf2f(h3[(size_t)m2 * 128 + t]);
        acc += bf2f(h2[(size_t)m3 * 128 + t]) + bf2f(h3[(size_t)m3 * 128 + t]);
    }
    for (; e < re; ++e) {
        int m = members[e];
        acc += bf2f(h2[(size_t)m * 128 + t]) + bf2f(h3[(size_t)m * 128 + t]);
    }
    float invc = 1.0f / fmaxf((float)(re - ro), 1.0f);
    zh[t] = acc * invc;
    __syncthreads();
    float a = bl1[t];
    for (int k = 0; k < 128; ++k)
        a += zh[k] * (Wl1[(size_t)k * 128 + t] + Wl1[(size_t)(k + 128) * 128 + t]);
    float zv = fmaxf(a, 0.f);
    float p = zv * Wl2[t];
    #pragma unroll
    for (int off = 32; off > 0; off >>= 1) p += __shfl_down(p, off, 64);
    if ((t & 63) == 0) partial[t >> 6] = p;
    __syncthreads();
    if (t == 0) out[c] = partial[0] + partial[1] + bl2[0];
}

extern "C" void kernel_launch(void* const* d_in, const int* in_sizes, int n_in,
                              void* d_out, int out_size, void* d_ws, size_t ws_size,
                              hipStream_t stream) {
    const float* x       = (const float*)d_in[0];
    const int*   edge    = (const int*)d_in[1];
    const int*   comm    = (const int*)d_in[2];
    const float* id_emb  = (const float*)d_in[3];
    const float* W1      = (const float*)d_in[4];
    const float* b1      = (const float*)d_in[5];
    const float* W2      = (const float*)d_in[6];
    const float* b2      = (const float*)d_in[7];
    const float* W3      = (const float*)d_in[8];
    const float* b3      = (const float*)d_in[9];
    const float* Wc1     = (const float*)d_in[10];
    const float* bc1     = (const float*)d_in[11];
    const float* Wc2     = (const float*)d_in[12];
    const float* bc2     = (const float*)d_in[13];
    const float* Wl1     = (const float*)d_in[14];
    const float* bl1     = (const float*)d_in[15];
    const float* Wl2     = (const float*)d_in[16];
    const float* bl2     = (const float*)d_in[17];
    float* out = (float*)d_out;
    float* ws  = (float*)d_ws;

    const int* srcIdx = edge;
    const int* dstIdx = edge + EE;

    size_t o = 0;
    auto alloc = [&](size_t nfloats) {
        float* p = ws + o; o += (nfloats + 3) & ~(size_t)3; return p;
    };
    float* dis      = alloc(NN);
    int* rowofs     = (int*)alloc(NN + 8);
    int* bucketCnt  = (int*)alloc(NBK + 8);
    int* bucketBase = (int*)alloc(NBK + 8);
    int* bucketFill = (int*)alloc(NBK + 8);
    int* commcnt    = (int*)alloc(1024);
    int* commofs    = (int*)alloc(1024 + 8);
    int* members    = (int*)alloc(NN);
    int2* bkt       = (int2*)alloc((size_t)EE * 2);
    int* csr        = (int*)alloc(EE);
    unsigned short* W3t  = (unsigned short*)alloc(320 * 328 / 2);
    unsigned short* Wc1t = (unsigned short*)alloc(128 * 328 / 2);
    unsigned short* Wc2t = (unsigned short*)alloc(128 * 136 / 2);
    unsigned short* h0   = (unsigned short*)alloc((size_t)NN * 320 / 2);
    unsigned short* h1   = (unsigned short*)alloc((size_t)NN * 320 / 2);
    unsigned char*  hw8  = (unsigned char*)alloc((size_t)NN * 128 / 4);
    unsigned short* h2   = (unsigned short*)alloc((size_t)NN * 128 / 2);
    unsigned short* h3   = (unsigned short*)alloc((size_t)NN * 128 / 2);

    // ---- bucketed CSR build + degree norm + community CSR ----
    k_init<<<4, 256, 0, stream>>>(bucketCnt, bucketFill, commcnt);
    k_bhist<<<NBK, 256, 0, stream>>>(dstIdx, bucketCnt);
    k_bscan<<<1, 512, 0, stream>>>(bucketCnt, bucketBase);
    k_bucketize<<<NBK, 256, 0, stream>>>(srcIdx, dstIdx, bucketBase, bucketFill, bkt);
    k_csr<<<NBK, 256, 0, stream>>>(bkt, bucketBase, comm, commcnt, rowofs, dis, csr);
    k_scanc<<<1, 1024, 0, stream>>>(commcnt, commofs);
    k_fillc<<<NBK, 256, 0, stream>>>(comm, commofs, commcnt, members);

    // ---- weight convert/transpose to bf16 (one launch) ----
    k_wconv<<<dim3(2, 576), 256, 0, stream>>>(W3, W3t, Wc1, Wc1t, Wc2, Wc2t);

    // ---- embedding (bf16 out) ----
    k_embed<<<(NN + 3) / 4, 256, 0, stream>>>(x, id_emb, W1, b1, W2, b2, h0);

    int rb = (NN + 127) / 128;   // 782
    // h1 = relu(h0 @ W3 + b3)   (3 col-tiles, ct fastest for A locality)
    k_bgemm<320, 320, 1, 0><<<rb * 3, 256, 0, stream>>>(h0, W3t, b3, h1, NN);
    // ---- conv1: hw8 = fp8(h1 @ Wc1 * SCALE) ----
    k_bgemm<320, 128, 0, 1><<<rb, 256, 0, stream>>>(h1, Wc1t, nullptr, hw8, NN);
    k_gather<<<(NN + 3) / 4, 256, 0, stream>>>(rowofs, csr, dis, hw8, bc1, h2);
    // ---- conv2: hw8 = fp8(h2 @ Wc2 * SCALE) ----
    k_bgemm<128, 128, 0, 1><<<rb, 256, 0, stream>>>(h2, Wc2t, nullptr, hw8, NN);
    k_gather<<<(NN + 3) / 4, 256, 0, stream>>>(rowofs, csr, dis, hw8, bc2, h3);

    // ---- final: pool + MLP ----
    k_final<<<CC, 128, 0, stream>>>(h2, h3, commofs, members, Wl1, bl1, Wl2, bl2, out);
}

// Round 11
// 378.141 us; speedup vs baseline: 1.9460x; 1.1098x over previous
//
#include <hip/hip_runtime.h>
#include <hip/hip_bf16.h>
#include <cstddef>

#define NN 100000
#define EE 1600000
#define CC 1000
#define NBK ((NN + 255) / 256)   // 391 dst buckets of 256 nodes
#define EPB 4096                  // edges per block in bucketize pass

#define FP8_SCALE 32.0f
#define FP8_INV   0.03125f

using short8 = __attribute__((ext_vector_type(8))) short;
using f32x4  = __attribute__((ext_vector_type(4))) float;
using f32x2  = __attribute__((ext_vector_type(2))) float;

__device__ __forceinline__ float bf2f(unsigned int u) {
    union { unsigned int i; float f; } x; x.i = u << 16; return x.f;
}
__device__ __forceinline__ unsigned short f2bf(float f) {
    __hip_bfloat16 h = __float2bfloat16(f);
    return *reinterpret_cast<unsigned short*>(&h);
}
__device__ __forceinline__ unsigned int pack2(float lo, float hi) {
    return ((unsigned int)f2bf(hi) << 16) | f2bf(lo);
}
__device__ __forceinline__ unsigned char f2fp8(float v) {
    unsigned int p = __builtin_amdgcn_cvt_pk_fp8_f32(v, v, 0, false);
    return (unsigned char)(p & 0xffu);
}
__device__ __forceinline__ f32x2 fp8x2f(unsigned int u16) {
    return __builtin_amdgcn_cvt_pk_f32_fp8(u16, false);
}

// ---------------- init: bucketCnt=0, bucketFill=0, commcnt=0 ----------------
__global__ void k_init(int* __restrict__ bucketCnt, int* __restrict__ bucketFill,
                       int* __restrict__ commcnt) {
    int i = blockIdx.x * 256 + threadIdx.x;   // grid covers 1024
    if (i < NBK) { bucketCnt[i] = 0; bucketFill[i] = 0; }
    if (i < CC) commcnt[i] = 0;
}

// ---------------- pass A0: bucket histogram (LDS-staged) ----------------
__global__ __launch_bounds__(256) void k_bhist(const int* __restrict__ dst,
                                               int* __restrict__ bucketCnt) {
    __shared__ int hist[NBK];
    int t = threadIdx.x;
    for (int i = t; i < NBK; i += 256) hist[i] = 0;
    __syncthreads();
    int base = blockIdx.x * EPB;
    for (int i = t; i < EPB; i += 256) {
        int e = base + i;
        if (e < EE) atomicAdd(&hist[dst[e] >> 8], 1);
    }
    __syncthreads();
    for (int i = t; i < NBK; i += 256)
        if (hist[i]) atomicAdd(&bucketCnt[i], hist[i]);
}

// ---------------- pass A-scan: exclusive scan of bucket counts (1 block) ----------------
__global__ void k_bscan(const int* __restrict__ bucketCnt, int* __restrict__ bucketBase) {
    __shared__ int sd[512];
    int t = threadIdx.x;
    int v = (t < NBK) ? bucketCnt[t] : 0;
    sd[t] = v;
    __syncthreads();
    for (int off = 1; off < 512; off <<= 1) {
        int x = (t >= off) ? sd[t - off] : 0;
        __syncthreads();
        sd[t] += x;
        __syncthreads();
    }
    if (t < NBK) bucketBase[t] = sd[t] - v;   // exclusive
    if (t == 0) bucketBase[NBK] = EE;
}

// ---------------- pass A1: partition edges into bucket regions ----------------
__global__ __launch_bounds__(256) void k_bucketize(
    const int* __restrict__ src, const int* __restrict__ dst,
    const int* __restrict__ bucketBase, int* __restrict__ bucketFill,
    int2* __restrict__ bkt) {
    __shared__ int hist[NBK];
    __shared__ int runPos[NBK];
    int t = threadIdx.x;
    for (int i = t; i < NBK; i += 256) hist[i] = 0;
    __syncthreads();
    int base = blockIdx.x * EPB;
    for (int i = t; i < EPB; i += 256) {
        int e = base + i;
        if (e < EE) atomicAdd(&hist[dst[e] >> 8], 1);
    }
    __syncthreads();
    for (int i = t; i < NBK; i += 256)
        runPos[i] = hist[i] ? (bucketBase[i] + atomicAdd(&bucketFill[i], hist[i])) : 0;
    __syncthreads();
    for (int i = t; i < EPB; i += 256) {
        int e = base + i;
        if (e < EE) {
            int d = dst[e];
            int pos = atomicAdd(&runPos[d >> 8], 1);
            bkt[pos] = make_int2(src[e], d);
        }
    }
}

// ---------------- pass B: per-bucket CSR finalize (rowofs, dis, commcnt, csr src) ----------------
__global__ __launch_bounds__(256) void k_csr(
    const int2* __restrict__ bkt, const int* __restrict__ bucketBase,
    const int* __restrict__ comm, int* __restrict__ commcnt,
    int* __restrict__ rowofs, float* __restrict__ dis, int* __restrict__ csr) {
    __shared__ int cnt[256], sd[256], cnt2[256];
    int b = blockIdx.x, t = threadIdx.x;
    int base = bucketBase[b], end = bucketBase[b + 1];
    int nodeBase = b << 8;
    cnt[t] = 0; cnt2[t] = 0;
    __syncthreads();
    for (int i = base + t; i < end; i += 256)
        atomicAdd(&cnt[bkt[i].y - nodeBase], 1);
    __syncthreads();
    int v = cnt[t];
    sd[t] = v;
    __syncthreads();
    for (int off = 1; off < 256; off <<= 1) {
        int x = (t >= off) ? sd[t - off] : 0;
        __syncthreads();
        sd[t] += x;
        __syncthreads();
    }
    int ofs = sd[t] - v;           // exclusive local offset
    sd[t] = ofs;
    int node = nodeBase + t;
    if (node < NN) {
        rowofs[node] = base + ofs;
        dis[node] = rsqrtf((float)v + 1.0f);
        atomicAdd(&commcnt[comm[node]], 1);
    }
    if (b == NBK - 1 && t == 0) rowofs[NN] = EE;
    __syncthreads();
    for (int i = base + t; i < end; i += 256) {
        int2 ed = bkt[i];
        int ld = ed.y - nodeBase;
        int p = atomicAdd(&cnt2[ld], 1);
        csr[base + sd[ld] + p] = ed.x;
    }
}

// ---------------- community scan (1 block over CC=1000) + zero commcnt ----------------
__global__ void k_scanc(int* __restrict__ commcnt, int* __restrict__ commofs) {
    __shared__ int sd[1024];
    int t = threadIdx.x;
    int v = (t < CC) ? commcnt[t] : 0;
    sd[t] = v;
    __syncthreads();
    for (int off = 1; off < 1024; off <<= 1) {
        int x = (t >= off) ? sd[t - off] : 0;
        __syncthreads();
        sd[t] += x;
        __syncthreads();
    }
    if (t < CC) {
        commofs[t] = sd[t] - v;        // exclusive
        commcnt[t] = 0;                // reset for fill pass
    }
    if (t == CC - 1) commofs[CC] = sd[t];
}

// ---------------- community member fill ----------------
__global__ void k_fillc(const int* __restrict__ comm, const int* __restrict__ commofs,
                        int* __restrict__ commcnt, int* __restrict__ members) {
    int i = blockIdx.x * 256 + threadIdx.x;
    if (i >= NN) return;
    int c = comm[i];
    int pos = commofs[c] + atomicAdd(&commcnt[c], 1);
    members[pos] = i;
}

// ---------------- weight convert+transpose (all 3): W[K][N] f32 -> Wt[N][K+8] bf16 ----------------
__global__ void k_wconv(const float* __restrict__ W3, unsigned short* __restrict__ W3t,
                        const float* __restrict__ Wc1, unsigned short* __restrict__ Wc1t,
                        const float* __restrict__ Wc2, unsigned short* __restrict__ Wc2t) {
    int y = blockIdx.y;
    int k = blockIdx.x * 256 + threadIdx.x;
    if (y < 320) {              // W3: K=320, N=320
        if (k < 328) W3t[(size_t)y * 328 + k] = (k < 320) ? f2bf(W3[(size_t)k * 320 + y]) : 0;
    } else if (y < 448) {       // Wc1: K=320, N=128
        int n = y - 320;
        if (k < 328) Wc1t[(size_t)n * 328 + k] = (k < 320) ? f2bf(Wc1[(size_t)k * 128 + n]) : 0;
    } else {                    // Wc2: K=128, N=128
        int n = y - 448;
        if (k < 136) Wc2t[(size_t)n * 136 + k] = (k < 128) ? f2bf(Wc2[(size_t)k * 128 + n]) : 0;
    }
}

// ---------------- embed (64 nodes/block): h0 = [relu(xW1+b1)|relu(xW2+b2)|id], bf16 ----------------
__global__ __launch_bounds__(256) void k_embed(
    const float* __restrict__ x, const float* __restrict__ id_emb,
    const float* __restrict__ W1, const float* __restrict__ b1,
    const float* __restrict__ W2, const float* __restrict__ b2,
    unsigned short* __restrict__ h0) {
    __shared__ float W1s[7][128];
    __shared__ float W2s[12][128];
    __shared__ float b1s[128], b2s[128];
    __shared__ float xs[64][20];
    int t = threadIdx.x;
    int base = blockIdx.x * 64;
    for (int i = t; i < 7 * 128; i += 256) ((float*)W1s)[i] = W1[i];
    for (int i = t; i < 12 * 128; i += 256) ((float*)W2s)[i] = W2[i];
    if (t < 128) { b1s[t] = b1[t]; b2s[t] = b2[t]; }
    for (int i = t; i < 64 * 19; i += 256) {
        int r = i / 19, cc = i % 19;
        int node = base + r;
        xs[r][cc] = (node < NN) ? x[(size_t)node * 19 + cc] : 0.f;
    }
    __syncthreads();
    int ln = t >> 6, lane = t & 63;
    int c2 = lane * 2;
    for (int nn = ln; nn < 64; nn += 4) {
        int node = base + nn;
        if (node >= NN) break;
        unsigned int* orow = (unsigned int*)(h0 + (size_t)node * 320);
        float a0 = b1s[c2], a1 = b1s[c2 + 1];
        #pragma unroll
        for (int k = 0; k < 7; ++k) {
            float xv = xs[nn][k];
            float2 w = *(const float2*)&W1s[k][c2];
            a0 += xv * w.x; a1 += xv * w.y;
        }
        orow[lane] = pack2(fmaxf(a0, 0.f), fmaxf(a1, 0.f));
        a0 = b2s[c2]; a1 = b2s[c2 + 1];
        #pragma unroll
        for (int k = 0; k < 12; ++k) {
            float xv = xs[nn][7 + k];
            float2 w = *(const float2*)&W2s[k][c2];
            a0 += xv * w.x; a1 += xv * w.y;
        }
        orow[64 + lane] = pack2(fmaxf(a0, 0.f), fmaxf(a1, 0.f));
        if (lane < 32) {
            float2 iv = *(const float2*)(id_emb + (size_t)node * 64 + c2);
            orow[128 + lane] = pack2(iv.x, iv.y);
        }
    }
}

// ---------------- unified bf16 MFMA GEMM, reg-prefetch pipeline + coalesced epilogue ----------------
// OUT8=0: C bf16 [+bias+relu].  OUT8=1 (N must be 128): C fp8 scaled by FP8_SCALE.
template <int K, int N, int RELU, int OUT8>
__global__ __launch_bounds__(256) void k_bgemm(
    const unsigned short* __restrict__ A, const unsigned short* __restrict__ Bt,
    const float* __restrict__ bias, void* __restrict__ Cv, int M) {
    constexpr int NT = (N + 127) / 128;
    __shared__ __align__(16) short sbuf[2 * 128 * 40];   // 20480 B: As | Bs, reused by epilogue
    short (*As)[40] = (short(*)[40])sbuf;
    short (*Bs)[40] = (short(*)[40])(sbuf + 128 * 40);
    int t = threadIdx.x;
    int bid = blockIdx.x;
    int ct = bid % NT, rblk = bid / NT;
    int rowBase = rblk * 128, colBase = ct * 128;
    int wid = t >> 6, lane = t & 63;
    int wm = wid >> 1, wn = wid & 1;
    int fr = lane & 15, g = lane >> 4;
    int rr = t >> 2;              // 0..63 staging row
    int qq = (t & 3) * 8;         // k-subchunk
    f32x4 acc[4][4] = {};
    short8 z = {};
    short8 pA0, pA1, pB0, pB1;
    int grA0 = rowBase + rr, grA1 = grA0 + 64;
    int gcB0 = colBase + rr, gcB1 = gcB0 + 64;
    // prefetch k=0
    pA0 = (grA0 < M) ? *(const short8*)(A + (size_t)grA0 * K + qq) : z;
    pA1 = (grA1 < M) ? *(const short8*)(A + (size_t)grA1 * K + qq) : z;
    pB0 = (gcB0 < N) ? *(const short8*)(Bt + (size_t)gcB0 * (K + 8) + qq) : z;
    pB1 = (gcB1 < N) ? *(const short8*)(Bt + (size_t)gcB1 * (K + 8) + qq) : z;
    for (int kb = 0; kb < K; kb += 32) {
        __syncthreads();                    // LDS consumers of prev step done
        *(short8*)&As[rr][qq]      = pA0;
        *(short8*)&As[rr + 64][qq] = pA1;
        *(short8*)&Bs[rr][qq]      = pB0;
        *(short8*)&Bs[rr + 64][qq] = pB1;
        __syncthreads();                    // LDS ready
        if (kb + 32 < K) {                  // issue next-step loads under MFMA
            int kn = kb + 32;
            pA0 = (grA0 < M) ? *(const short8*)(A + (size_t)grA0 * K + kn + qq) : z;
            pA1 = (grA1 < M) ? *(const short8*)(A + (size_t)grA1 * K + kn + qq) : z;
            pB0 = (gcB0 < N) ? *(const short8*)(Bt + (size_t)gcB0 * (K + 8) + kn + qq) : z;
            pB1 = (gcB1 < N) ? *(const short8*)(Bt + (size_t)gcB1 * (K + 8) + kn + qq) : z;
        }
        short8 bfr[4];
        #pragma unroll
        for (int nf = 0; nf < 4; ++nf)
            bfr[nf] = *(const short8*)&Bs[wn * 64 + nf * 16 + fr][g * 8];
        #pragma unroll
        for (int mf = 0; mf < 4; ++mf) {
            short8 a = *(const short8*)&As[wm * 64 + mf * 16 + fr][g * 8];
            #pragma unroll
            for (int nf = 0; nf < 4; ++nf)
                acc[mf][nf] = __builtin_amdgcn_mfma_f32_16x16x32_bf16(a, bfr[nf], acc[mf][nf], 0, 0, 0);
        }
    }
    // ---- epilogue: LDS transpose -> coalesced 16B stores ----
    if (!OUT8) {
        unsigned short* sb = (unsigned short*)sbuf;
        #pragma unroll
        for (int cc = 0; cc < 2; ++cc) {
            int cbase = colBase + cc * 64;
            if (cbase < N) {                       // uniform per block
                __syncthreads();
                if (wn == cc) {
                    #pragma unroll
                    for (int nf = 0; nf < 4; ++nf) {
                        int colL = nf * 16 + fr;
                        float bv = RELU ? bias[cbase + colL] : 0.f;
                        #pragma unroll
                        for (int mf = 0; mf < 4; ++mf) {
                            #pragma unroll
                            for (int r = 0; r < 4; ++r) {
                                int row = wm * 64 + mf * 16 + g * 4 + r;
                                float v = acc[mf][nf][r];
                                if (RELU) v = fmaxf(v + bv, 0.f);
                                sb[row * 64 + colL] = f2bf(v);
                            }
                        }
                    }
                }
                __syncthreads();
                #pragma unroll
                for (int i = 0; i < 4; ++i) {
                    int off8 = t + 256 * i;        // 16-B chunk id (1024 total)
                    int row = off8 >> 3;
                    int col = (off8 & 7) * 8;
                    int grow = rowBase + row;
                    if (grow < M)
                        *(short8*)((unsigned short*)Cv + (size_t)grow * N + cbase + col) =
                            *(const short8*)&sb[row * 64 + col];
                }
            }
        }
    } else {
        unsigned char* sb8 = (unsigned char*)sbuf;  // 128x128 fp8 tile = 16 KB
        __syncthreads();
        #pragma unroll
        for (int nf = 0; nf < 4; ++nf) {
            int colL = wn * 64 + nf * 16 + fr;
            #pragma unroll
            for (int mf = 0; mf < 4; ++mf) {
                #pragma unroll
                for (int r = 0; r < 4; ++r) {
                    int row = wm * 64 + mf * 16 + g * 4 + r;
                    sb8[row * 128 + colL] = f2fp8(acc[mf][nf][r] * FP8_SCALE);
                }
            }
        }
        __syncthreads();
        #pragma unroll
        for (int i = 0; i < 4; ++i) {
            int off16 = t + 256 * i;               // 16-B chunk id (1024 total)
            int row = off16 >> 3;
            int col = (off16 & 7) * 16;
            int grow = rowBase + row;
            if (grow < M)
                *(int4*)((unsigned char*)Cv + (size_t)grow * N + col) =
                    *(const int4*)&sb8[row * 128 + col];
        }
    }
}

// ---------------- pure gather conv (fp8 in / bf16 out):
// h = relu(dis[d]*(sum hw8[src]*dis[src] + hw8[d]*dis[d])/SCALE + b) ----------------
__global__ __launch_bounds__(256) void k_gather(
    const int* __restrict__ rowofs, const int* __restrict__ csr,
    const float* __restrict__ dis, const unsigned char* __restrict__ hw8,
    const float* __restrict__ bias, unsigned short* __restrict__ hout) {
    int wid = blockIdx.x * 4 + (threadIdx.x >> 6);
    wid = __builtin_amdgcn_readfirstlane(wid);
    int lane = threadIdx.x & 63;
    if (wid >= NN) return;
    int ro = rowofs[wid], re = rowofs[wid + 1];
    int c = lane * 2;
    float dsd = dis[wid];
    unsigned int hv = *(const unsigned short*)(hw8 + (size_t)wid * 128 + c);
    f32x2 hf = fp8x2f(hv);
    float a0 = hf.x * dsd;           // scaled space; final multiply by dsd
    float a1 = hf.y * dsd;
    int e = ro;
    for (; e + 16 <= re; e += 16) {
        int s[16]; float n[16]; unsigned int v[16];
        #pragma unroll
        for (int j = 0; j < 16; ++j) s[j] = csr[e + j];
        #pragma unroll
        for (int j = 0; j < 16; ++j) n[j] = dis[s[j]];
        #pragma unroll
        for (int j = 0; j < 16; ++j)
            v[j] = *(const unsigned short*)(hw8 + (size_t)s[j] * 128 + c);
        #pragma unroll
        for (int j = 0; j < 16; ++j) {
            f32x2 f = fp8x2f(v[j]);
            a0 += f.x * n[j];
            a1 += f.y * n[j];
        }
    }
    for (; e + 4 <= re; e += 4) {
        int s[4]; float n[4]; unsigned int v[4];
        #pragma unroll
        for (int j = 0; j < 4; ++j) s[j] = csr[e + j];
        #pragma unroll
        for (int j = 0; j < 4; ++j) n[j] = dis[s[j]];
        #pragma unroll
        for (int j = 0; j < 4; ++j)
            v[j] = *(const unsigned short*)(hw8 + (size_t)s[j] * 128 + c);
        #pragma unroll
        for (int j = 0; j < 4; ++j) {
            f32x2 f = fp8x2f(v[j]);
            a0 += f.x * n[j];
            a1 += f.y * n[j];
        }
    }
    for (; e < re; ++e) {
        int s0 = csr[e];
        float n0 = dis[s0];
        unsigned int v0 = *(const unsigned short*)(hw8 + (size_t)s0 * 128 + c);
        f32x2 f = fp8x2f(v0);
        a0 += f.x * n0;
        a1 += f.y * n0;
    }
    a0 = fmaxf(a0 * dsd * FP8_INV + bias[c], 0.f);
    a1 = fmaxf(a1 * dsd * FP8_INV + bias[c + 1], 0.f);
    *(unsigned int*)(hout + (size_t)wid * 128 + c) = pack2(a0, a1);
}

// ---------------- final: community pool (CSR, no atomics) + MLP ----------------
__global__ __launch_bounds__(128) void k_final(
    const unsigned short* __restrict__ h2, const unsigned short* __restrict__ h3,
    const int* __restrict__ commofs, const int* __restrict__ members,
    const float* __restrict__ Wl1, const float* __restrict__ bl1,
    const float* __restrict__ Wl2, const float* __restrict__ bl2,
    float* __restrict__ out) {
    __shared__ float zh[128];
    __shared__ float partial[2];
    int c = blockIdx.x, t = threadIdx.x;
    int ro = commofs[c], re = commofs[c + 1];
    float acc = 0.f;
    int e = ro;
    for (; e + 4 <= re; e += 4) {
        int m0 = members[e], m1 = members[e + 1];
        int m2 = members[e + 2], m3 = members[e + 3];
        acc += bf2f(h2[(size_t)m0 * 128 + t]) + bf2f(h3[(size_t)m0 * 128 + t]);
        acc += bf2f(h2[(size_t)m1 * 128 + t]) + bf2f(h3[(size_t)m1 * 128 + t]);
        acc += bf2f(h2[(size_t)m2 * 128 + t]) + bf2f(h3[(size_t)m2 * 128 + t]);
        acc += bf2f(h2[(size_t)m3 * 128 + t]) + bf2f(h3[(size_t)m3 * 128 + t]);
    }
    for (; e < re; ++e) {
        int m = members[e];
        acc += bf2f(h2[(size_t)m * 128 + t]) + bf2f(h3[(size_t)m * 128 + t]);
    }
    float invc = 1.0f / fmaxf((float)(re - ro), 1.0f);
    zh[t] = acc * invc;
    __syncthreads();
    float a = bl1[t];
    for (int k = 0; k < 128; ++k)
        a += zh[k] * (Wl1[(size_t)k * 128 + t] + Wl1[(size_t)(k + 128) * 128 + t]);
    float zv = fmaxf(a, 0.f);
    float p = zv * Wl2[t];
    #pragma unroll
    for (int off = 32; off > 0; off >>= 1) p += __shfl_down(p, off, 64);
    if ((t & 63) == 0) partial[t >> 6] = p;
    __syncthreads();
    if (t == 0) out[c] = partial[0] + partial[1] + bl2[0];
}

extern "C" void kernel_launch(void* const* d_in, const int* in_sizes, int n_in,
                              void* d_out, int out_size, void* d_ws, size_t ws_size,
                              hipStream_t stream) {
    const float* x       = (const float*)d_in[0];
    const int*   edge    = (const int*)d_in[1];
    const int*   comm    = (const int*)d_in[2];
    const float* id_emb  = (const float*)d_in[3];
    const float* W1      = (const float*)d_in[4];
    const float* b1      = (const float*)d_in[5];
    const float* W2      = (const float*)d_in[6];
    const float* b2      = (const float*)d_in[7];
    const float* W3      = (const float*)d_in[8];
    const float* b3      = (const float*)d_in[9];
    const float* Wc1     = (const float*)d_in[10];
    const float* bc1     = (const float*)d_in[11];
    const float* Wc2     = (const float*)d_in[12];
    const float* bc2     = (const float*)d_in[13];
    const float* Wl1     = (const float*)d_in[14];
    const float* bl1     = (const float*)d_in[15];
    const float* Wl2     = (const float*)d_in[16];
    const float* bl2     = (const float*)d_in[17];
    float* out = (float*)d_out;
    float* ws  = (float*)d_ws;

    const int* srcIdx = edge;
    const int* dstIdx = edge + EE;

    size_t o = 0;
    auto alloc = [&](size_t nfloats) {
        float* p = ws + o; o += (nfloats + 3) & ~(size_t)3; return p;
    };
    float* dis      = alloc(NN);
    int* rowofs     = (int*)alloc(NN + 8);
    int* bucketCnt  = (int*)alloc(NBK + 8);
    int* bucketBase = (int*)alloc(NBK + 8);
    int* bucketFill = (int*)alloc(NBK + 8);
    int* commcnt    = (int*)alloc(1024);
    int* commofs    = (int*)alloc(1024 + 8);
    int* members    = (int*)alloc(NN);
    int2* bkt       = (int2*)alloc((size_t)EE * 2);
    int* csr        = (int*)alloc(EE);
    unsigned short* W3t  = (unsigned short*)alloc(320 * 328 / 2);
    unsigned short* Wc1t = (unsigned short*)alloc(128 * 328 / 2);
    unsigned short* Wc2t = (unsigned short*)alloc(128 * 136 / 2);
    unsigned short* h0   = (unsigned short*)alloc((size_t)NN * 320 / 2);
    unsigned short* h1   = (unsigned short*)alloc((size_t)NN * 320 / 2);
    unsigned char*  hw8  = (unsigned char*)alloc((size_t)NN * 128 / 4);
    unsigned short* h2   = (unsigned short*)alloc((size_t)NN * 128 / 2);
    unsigned short* h3   = (unsigned short*)alloc((size_t)NN * 128 / 2);

    // ---- bucketed CSR build + degree norm + community CSR ----
    k_init<<<4, 256, 0, stream>>>(bucketCnt, bucketFill, commcnt);
    k_bhist<<<NBK, 256, 0, stream>>>(dstIdx, bucketCnt);
    k_bscan<<<1, 512, 0, stream>>>(bucketCnt, bucketBase);
    k_bucketize<<<NBK, 256, 0, stream>>>(srcIdx, dstIdx, bucketBase, bucketFill, bkt);
    k_csr<<<NBK, 256, 0, stream>>>(bkt, bucketBase, comm, commcnt, rowofs, dis, csr);
    k_scanc<<<1, 1024, 0, stream>>>(commcnt, commofs);
    k_fillc<<<NBK, 256, 0, stream>>>(comm, commofs, commcnt, members);

    // ---- weight convert/transpose to bf16 (one launch) ----
    k_wconv<<<dim3(2, 576), 256, 0, stream>>>(W3, W3t, Wc1, Wc1t, Wc2, Wc2t);

    // ---- embedding (bf16 out, 64 nodes/block) ----
    k_embed<<<(NN + 63) / 64, 256, 0, stream>>>(x, id_emb, W1, b1, W2, b2, h0);

    int rb = (NN + 127) / 128;   // 782
    // h1 = relu(h0 @ W3 + b3)   (3 col-tiles, ct fastest for A locality)
    k_bgemm<320, 320, 1, 0><<<rb * 3, 256, 0, stream>>>(h0, W3t, b3, h1, NN);
    // ---- conv1: hw8 = fp8(h1 @ Wc1 * SCALE) ----
    k_bgemm<320, 128, 0, 1><<<rb, 256, 0, stream>>>(h1, Wc1t, nullptr, hw8, NN);
    k_gather<<<(NN + 3) / 4, 256, 0, stream>>>(rowofs, csr, dis, hw8, bc1, h2);
    // ---- conv2: hw8 = fp8(h2 @ Wc2 * SCALE) ----
    k_bgemm<128, 128, 0, 1><<<rb, 256, 0, stream>>>(h2, Wc2t, nullptr, hw8, NN);
    k_gather<<<(NN + 3) / 4, 256, 0, stream>>>(rowofs, csr, dis, hw8, bc2, h3);

    // ---- final: pool + MLP ----
    k_final<<<CC, 128, 0, stream>>>(h2, h3, commofs, members, Wl1, bl1, Wl2, bl2, out);
}